// Round 7
// baseline (537.722 us; speedup 1.0000x reference)
//
#include <hip/hip_runtime.h>

#define NN 512
#define CCH 128
#define MM (NN*NN)   // 262144

using f32x4  = __attribute__((ext_vector_type(4))) float;
using f32x2  = __attribute__((ext_vector_type(2))) float;
using bf16x8 = __attribute__((ext_vector_type(8))) short;
using u16x4  = __attribute__((ext_vector_type(4))) unsigned short;
using u32x2  = __attribute__((ext_vector_type(2))) unsigned int;
using u32x4  = __attribute__((ext_vector_type(4))) unsigned int;
typedef unsigned short u16;

__device__ __forceinline__ u16 f2bf(float f) {
    unsigned u = __builtin_bit_cast(unsigned, f);
    u += 0x7FFF + ((u >> 16) & 1);
    return (u16)(u >> 16);
}
__device__ __forceinline__ float bf2f(u16 h) {
    unsigned u = ((unsigned)h) << 16;
    return __builtin_bit_cast(float, u);
}
__device__ __forceinline__ unsigned pack2(float lo, float hi) {
    return (unsigned)f2bf(lo) | ((unsigned)f2bf(hi) << 16);
}
__device__ __forceinline__ float sigm(float x) { return 1.0f / (1.0f + __expf(-x)); }

__device__ __forceinline__ void gl_lds16(const void* g, void* l) {
    __builtin_amdgcn_global_load_lds(
        (const __attribute__((address_space(1))) void*)g,
        (__attribute__((address_space(3))) void*)l, 16, 0, 0);
}

// ---------------- k_prep: fold LN gamma/beta into bf16 weights + biases ----
// Weight rows stored CHUNK-SWIZZLED: logical 16B chunk q of row o lives at
// physical chunk (q ^ (o&7)).
__global__ __launch_bounds__(256) void k_prep(
    const float* __restrict__ w0, const float* __restrict__ w1,
    const float* __restrict__ w2, const float* __restrict__ w3,
    const float* __restrict__ w4, const float* __restrict__ w5,
    const float* __restrict__ b0, const float* __restrict__ b1,
    const float* __restrict__ b2, const float* __restrict__ b3,
    const float* __restrict__ b4, const float* __restrict__ b5,
    const float* __restrict__ gin, const float* __restrict__ bin,
    const float* __restrict__ gout, const float* __restrict__ bout,
    u16* __restrict__ wbf, float* __restrict__ bias2) {
    int mat = blockIdx.x;
    const float* W = mat==0?w0:mat==1?w1:mat==2?w2:mat==3?w3:mat==4?w4:w5;
    const float* B = mat==0?b0:mat==1?b1:mat==2?b2:mat==3?b3:mat==4?b4:b5;
    const float* G = (mat==5)? gout : gin;
    const float* Bt= (mat==5)? bout : bin;
    __shared__ float gs[CCH], bs[CCH];
    int tid = threadIdx.x;
    if (tid < CCH) { gs[tid] = G[tid]; bs[tid] = Bt[tid]; }
    __syncthreads();
    int o = tid >> 1, c0 = (tid & 1) * 64;
    const float* src = W + o * CCH + c0;
    char* dstrow = (char*)(wbf + mat * 16384) + o * 256;
    int key = o & 7;
    float dot = 0.f;
    #pragma unroll
    for (int q = 0; q < 16; ++q) {
        f32x4 v = *(const f32x4*)(src + q * 4);
        int c = c0 + q * 4;
        dot += bs[c]*v.x + bs[c+1]*v.y + bs[c+2]*v.z + bs[c+3]*v.w;
        u16x4 p;
        p.x = f2bf(v.x * gs[c]);     p.y = f2bf(v.y * gs[c+1]);
        p.z = f2bf(v.z * gs[c+2]);   p.w = f2bf(v.w * gs[c+3]);
        int chunk = (c0 >> 3) + (q >> 1);
        *(u16x4*)(dstrow + (((chunk ^ key)) << 4) + ((q & 1) << 3)) = p;
    }
    dot += __shfl_xor(dot, 1);
    if ((tid & 1) == 0) bias2[mat * CCH + o] = B[o] + dot;
}

// ---------------- k_ln: LN(z) -> zn (bf16, odd 256B halves of d_out) ------
__global__ __launch_bounds__(256) void k_ln(const float* __restrict__ z,
                                            u16* __restrict__ dz) {
    int tid = threadIdx.x;
    int w = tid >> 6, lane = tid & 63;
    long row = (long)blockIdx.x * 4 + w;
    f32x2 v = *(const f32x2*)(z + row * CCH + lane * 2);
    float s = v.x + v.y, s2 = v.x * v.x + v.y * v.y;
    #pragma unroll
    for (int off = 32; off; off >>= 1) {
        s  += __shfl_xor(s, off);
        s2 += __shfl_xor(s2, off);
    }
    float mu  = s * (1.0f / CCH);
    float var = fmaxf(s2 * (1.0f / CCH) - mu * mu, 0.f);
    float rs  = rsqrtf(var + 1e-5f);
    unsigned pk = pack2((v.x - mu) * rs, (v.y - mu) * rs);
    *(unsigned*)(dz + row * 256 + 128 + lane * 2) = pk;
}

// ---------------- k_proj: PERSISTENT projection blocks ---------------------
// grid (171, 2, 3). Each block stages its weight pair ONCE, then grid-strides
// over all 4096 m-tiles with no barriers in the loop.
// mode 0: a-pair -> aT; mode 1: b-pair -> bT; mode 2: gate -> d_out row heads.
__global__ __launch_bounds__(256, 4) void k_proj(
    const u16* dz, const float* __restrict__ mask,
    const u16* __restrict__ wbf, const float* __restrict__ bias2,
    u16* __restrict__ aT, u16* __restrict__ bT) {
    __shared__ __align__(16) u16 w1s[8192];   // 16KB: 64 rows x 256B (swizzled)
    __shared__ __align__(16) u16 w2s[8192];
    int tid = threadIdx.x, w = tid >> 6, lane = tid & 63;
    int r = lane & 15, kq = lane >> 4;
    int ch = blockIdx.y, mode = blockIdx.z;
    int mat1 = (mode == 2) ? 4 : mode * 2;

    const char* W1g = (const char*)wbf + (size_t)(mat1 * 16384 + ch * 64 * CCH) * 2;
    const char* W2g = (const char*)wbf + (size_t)((mat1 + 1) * 16384 + ch * 64 * CCH) * 2;
    #pragma unroll
    for (int it = 0; it < 4; ++it) {
        long off = (long)it * 4096 + tid * 16;
        gl_lds16(W1g + off, (char*)w1s + it * 4096 + w * 1024);
        if (mode < 2) gl_lds16(W2g + off, (char*)w2s + it * 4096 + w * 1024);
    }
    __syncthreads();

    if (mode < 2) {
        // hoisted loop invariants
        u16* dst = mode ? bT : aT;
        const float* B1 = bias2 + mat1 * CCH + ch * 64;
        const float* B2 = bias2 + (mat1 + 1) * CCH + ch * 64;
        float b1v[4], b2v[4];
        char* dptr[4];
        #pragma unroll
        for (int nt = 0; nt < 4; ++nt) {
            int cc = nt * 16 + r;
            b1v[nt] = B1[cc];
            b2v[nt] = B2[cc];
            dptr[nt] = (char*)(dst + (long)(ch * 64 + cc) * MM);
        }
        int q = w * 2 + (kq >> 1);
        int sub8 = (kq & 1) << 3;

        for (int mt = blockIdx.x; mt < MM / 64; mt += gridDim.x) {
            long m0 = (long)mt * 64;
            int i7 = (mt >> 3) & 7;
            long mrow = m0 + w * 16 + r;
            bf16x8 av[4];
            #pragma unroll
            for (int kb = 0; kb < 4; ++kb)
                av[kb] = *(const bf16x8*)(dz + mrow * 256 + 128 + kb * 32 + kq * 8);
            f32x4 mkv = *(const f32x4*)(mask + m0 + w * 16 + kq * 4);

            f32x4 acc1[4], acc2[4];
            #pragma unroll
            for (int nt = 0; nt < 4; ++nt) { acc1[nt] = {0,0,0,0}; acc2[nt] = {0,0,0,0}; }
            #pragma unroll
            for (int nt = 0; nt < 4; ++nt) {
                int ol = nt * 16 + r;
                int key = ol & 7;
                const char* row1 = (const char*)w1s + ol * 256;
                const char* row2 = (const char*)w2s + ol * 256;
                #pragma unroll
                for (int kb = 0; kb < 4; ++kb) {
                    int ph = ((kb * 4 + kq) ^ key) << 4;
                    bf16x8 b1 = *(const bf16x8*)(row1 + ph);
                    bf16x8 b2 = *(const bf16x8*)(row2 + ph);
                    acc1[nt] = __builtin_amdgcn_mfma_f32_16x16x32_bf16(av[kb], b1, acc1[nt], 0, 0, 0);
                    acc2[nt] = __builtin_amdgcn_mfma_f32_16x16x32_bf16(av[kb], b2, acc2[nt], 0, 0, 0);
                }
            }
            long boff = m0 * 2 + (long)((q ^ i7) << 4) + sub8;
            #pragma unroll
            for (int nt = 0; nt < 4; ++nt) {
                float v0 = mkv[0] * sigm(acc1[nt][0] + b1v[nt]) * (acc2[nt][0] + b2v[nt]);
                float v1 = mkv[1] * sigm(acc1[nt][1] + b1v[nt]) * (acc2[nt][1] + b2v[nt]);
                float v2 = mkv[2] * sigm(acc1[nt][2] + b1v[nt]) * (acc2[nt][2] + b2v[nt]);
                float v3 = mkv[3] * sigm(acc1[nt][3] + b1v[nt]) * (acc2[nt][3] + b2v[nt]);
                u32x2 pv; pv.x = pack2(v0, v1); pv.y = pack2(v2, v3);
                *(u32x2*)(dptr[nt] + boff) = pv;
            }
        }
    } else {
        // gate: mfma(W, zn): j-regs -> 4 consecutive c; col r -> m-row
        f32x4 bg[4];
        #pragma unroll
        for (int nt = 0; nt < 4; ++nt)
            bg[nt] = *(const f32x4*)(bias2 + 4 * CCH + ch * 64 + nt * 16 + kq * 4);
        int c0base = ch * 64 + kq * 4;

        for (int mt = blockIdx.x; mt < MM / 64; mt += gridDim.x) {
            long m0 = (long)mt * 64;
            long mrow = m0 + w * 16 + r;
            bf16x8 av[4];
            #pragma unroll
            for (int kb = 0; kb < 4; ++kb)
                av[kb] = *(const bf16x8*)(dz + mrow * 256 + 128 + kb * 32 + kq * 8);

            f32x4 acc[4];
            #pragma unroll
            for (int nt = 0; nt < 4; ++nt) acc[nt] = {0,0,0,0};
            #pragma unroll
            for (int nt = 0; nt < 4; ++nt) {
                int ol = nt * 16 + r;
                int key = ol & 7;
                const char* row1 = (const char*)w1s + ol * 256;
                #pragma unroll
                for (int kb = 0; kb < 4; ++kb) {
                    bf16x8 b1 = *(const bf16x8*)(row1 + (((kb * 4 + kq) ^ key) << 4));
                    acc[nt] = __builtin_amdgcn_mfma_f32_16x16x32_bf16(b1, av[kb], acc[nt], 0, 0, 0);
                }
            }
            #pragma unroll
            for (int nt = 0; nt < 4; ++nt) {
                u32x2 pv;
                pv.x = pack2(sigm(acc[nt][0] + bg[nt][0]), sigm(acc[nt][1] + bg[nt][1]));
                pv.y = pack2(sigm(acc[nt][2] + bg[nt][2]), sigm(acc[nt][3] + bg[nt][3]));
                *(u32x2*)((u16*)dz + mrow * 256 + c0base + nt * 16) = pv;
            }
        }
    }
}

// ---------------- k_tri: per-channel triangle GEMM, BK=64 ------------------
// swapped mfma: j-regs -> 4 consecutive j-columns -> packed 8B stores
__global__ __launch_bounds__(256, 4) void k_tri(const u16* __restrict__ aT,
                                                const u16* __restrict__ bT,
                                                u16* __restrict__ xT) {
    __shared__ __align__(16) u16 At[128 * 64];  // 16KB
    __shared__ __align__(16) u16 Bt[128 * 64];
    int tid = threadIdx.x;
    int w = tid >> 6, lane = tid & 63;
    int r = lane & 15, kq = lane >> 4;

    int L = blockIdx.x;
    int xcd = L & 7, idx = L >> 3;
    int c    = xcd + 8 * (idx >> 4);
    int tile = idx & 15;
    int ti = tile >> 2, tj = tile & 3;

    const char* abase = (const char*)(aT + (long)c * MM) + (long)(ti * 128) * 1024;
    const char* bbase = (const char*)(bT + (long)c * MM) + (long)(tj * 128) * 1024;
    int wm = w >> 1, wn = w & 1;

    f32x4 acc[4][4];
    #pragma unroll
    for (int a = 0; a < 4; ++a)
        #pragma unroll
        for (int bq = 0; bq < 4; ++bq) acc[a][bq] = {0.f,0.f,0.f,0.f};

    for (int ks = 0; ks < 8; ++ks) {
        const char* asrc = abase + ks * 128;
        const char* bsrc = bbase + ks * 128;
        #pragma unroll
        for (int it = 0; it < 4; ++it) {
            int u = it * 256 + tid;
            long goff = (long)(u >> 3) * 1024 + (u & 7) * 16;
            gl_lds16(asrc + goff, (char*)At + it * 4096 + w * 1024);
            gl_lds16(bsrc + goff, (char*)Bt + it * 4096 + w * 1024);
        }
        __syncthreads();

        #pragma unroll
        for (int kh = 0; kh < 2; ++kh) {
            bf16x8 af[4];
            #pragma unroll
            for (int mt = 0; mt < 4; ++mt) {
                int rowa = wm * 64 + mt * 16 + r;
                af[mt] = *(const bf16x8*)((const char*)At + rowa * 128 +
                                          (((kh * 4 + kq) ^ (r & 7)) << 4));
            }
            #pragma unroll
            for (int nt = 0; nt < 4; ++nt) {
                int rowb = wn * 64 + nt * 16 + r;
                bf16x8 bf = *(const bf16x8*)((const char*)Bt + rowb * 128 +
                                             (((kh * 4 + kq) ^ (r & 7)) << 4));
                #pragma unroll
                for (int mt = 0; mt < 4; ++mt)
                    acc[mt][nt] = __builtin_amdgcn_mfma_f32_16x16x32_bf16(bf, af[mt], acc[mt][nt], 0, 0, 0);
            }
        }
        __syncthreads();
    }

    // col r = i-row, j-regs = consecutive j
    u16* xbase = xT + (long)c * MM;
    int gi0 = ti * 128 + wm * 64;
    int gj0 = tj * 128 + wn * 64;
    #pragma unroll
    for (int mt = 0; mt < 4; ++mt) {
        long row = gi0 + mt * 16 + r;
        #pragma unroll
        for (int nt = 0; nt < 4; ++nt) {
            int col = gj0 + nt * 16 + kq * 4;
            u32x2 pv;
            pv.x = pack2(acc[mt][nt][0], acc[mt][nt][1]);
            pv.y = pack2(acc[mt][nt][2], acc[mt][nt][3]);
            *(u32x2*)(xbase + row * NN + col) = pv;
        }
    }
}

// ---------------- k_out: LN(x) @ w_z''^T + bias2_z, * gate -----------------
// swapped mfma: j-regs -> 4 consecutive c -> f32x4 stores
__global__ __launch_bounds__(256, 4) void k_out(const u16* __restrict__ xT,
                                                const u16* __restrict__ wbf,
                                                const float* __restrict__ bias2,
                                                const u16* gateB,
                                                float* __restrict__ outp) {
    __shared__ __align__(16) u16 xl[64 * 128];  // 16KB
    int tid = threadIdx.x, w = tid >> 6, lane = tid & 63;
    int r = lane & 15, kq = lane >> 4;
    long m0 = (long)blockIdx.x * 64;

    // transpose stage: xT[c][m] -> xl[m][c], 4 channels packed per u16x4
    {
        int cg = tid & 31, ms = tid >> 5;
        int c0 = cg * 4;
        const u16* base = xT + m0 + (long)ms * 8;
        bf16x8 v0 = *(const bf16x8*)(base + (long)(c0 + 0) * MM);
        bf16x8 v1 = *(const bf16x8*)(base + (long)(c0 + 1) * MM);
        bf16x8 v2 = *(const bf16x8*)(base + (long)(c0 + 2) * MM);
        bf16x8 v3 = *(const bf16x8*)(base + (long)(c0 + 3) * MM);
        #pragma unroll
        for (int e = 0; e < 8; ++e) {
            int m = ms * 8 + e;
            u16x4 t;
            t.x = (u16)v0[e]; t.y = (u16)v1[e]; t.z = (u16)v2[e]; t.w = (u16)v3[e];
            *(u16x4*)((char*)xl + m * 256 + ((c0 * 2) ^ ((m & 15) << 4))) = t;
        }
    }
    __syncthreads();

    // A-frags as u32 pairs + LN stats via mask/shift decode
    int mlr = w * 16 + r;
    int swm = (mlr & 15) << 4;
    u32x4 avu[4];
    float s = 0.f, s2 = 0.f;
    #pragma unroll
    for (int kb = 0; kb < 4; ++kb) {
        avu[kb] = *(const u32x4*)((const char*)xl + mlr * 256 + ((kb * 64 + kq * 16) ^ swm));
        #pragma unroll
        for (int p = 0; p < 4; ++p) {
            unsigned u = avu[kb][p];
            float flo = __builtin_bit_cast(float, u << 16);
            float fhi = __builtin_bit_cast(float, u & 0xFFFF0000u);
            s += flo + fhi;
            s2 = fmaf(flo, flo, s2);
            s2 = fmaf(fhi, fhi, s2);
        }
    }
    s  += __shfl_xor(s, 16);  s  += __shfl_xor(s, 32);
    s2 += __shfl_xor(s2, 16); s2 += __shfl_xor(s2, 32);
    float mu = s * (1.0f / CCH);
    float var = fmaxf(s2 * (1.0f / CCH) - mu * mu, 0.f);
    float rs = rsqrtf(var + 1e-5f);
    float nmu = -mu * rs;
    bf16x8 av[4];
    #pragma unroll
    for (int kb = 0; kb < 4; ++kb) {
        u32x4 o;
        #pragma unroll
        for (int p = 0; p < 4; ++p) {
            unsigned u = avu[kb][p];
            float flo = __builtin_bit_cast(float, u << 16);
            float fhi = __builtin_bit_cast(float, u & 0xFFFF0000u);
            o[p] = pack2(fmaf(flo, rs, nmu), fmaf(fhi, rs, nmu));
        }
        av[kb] = __builtin_bit_cast(bf16x8, o);
    }

    // gate preload (gateB aliases outp rows of THIS block only)
    long m = m0 + w * 16 + r;
    u16x4 gvu[8];
    #pragma unroll
    for (int nt = 0; nt < 8; ++nt)
        gvu[nt] = *(const u16x4*)(gateB + m * 256 + nt * 16 + kq * 4);

    // swapped MFMA vs w_z'' (global reads, chunk-swizzled layout)
    const char* Wz = (const char*)(wbf + 5 * 16384);
    f32x4 acc[8];
    #pragma unroll
    for (int nt = 0; nt < 8; ++nt) acc[nt] = {0,0,0,0};
    #pragma unroll
    for (int nt = 0; nt < 8; ++nt) {
        int ol = nt * 16 + r;
        int key = ol & 7;
        const char* row = Wz + ol * 256;
        #pragma unroll
        for (int kb = 0; kb < 4; ++kb) {
            bf16x8 bw = *(const bf16x8*)(row + (((kb * 4 + kq) ^ key) << 4));
            acc[nt] = __builtin_amdgcn_mfma_f32_16x16x32_bf16(bw, av[kb], acc[nt], 0, 0, 0);
        }
    }

    __syncthreads();   // ALL gate loads done before any aliasing store

    const float* b2z = bias2 + 5 * CCH;
    #pragma unroll
    for (int nt = 0; nt < 8; ++nt) {
        int c0 = nt * 16 + kq * 4;
        f32x4 bb = *(const f32x4*)(b2z + c0);
        f32x4 o;
        #pragma unroll
        for (int j = 0; j < 4; ++j)
            o[j] = (acc[nt][j] + bb[j]) * bf2f(gvu[nt][j]);
        *(f32x4*)(outp + m * CCH + c0) = o;
    }
}

extern "C" void kernel_launch(void* const* d_in, const int* in_sizes, int n_in,
                              void* d_out, int out_size, void* d_ws, size_t ws_size,
                              hipStream_t stream) {
    const float* z       = (const float*)d_in[0];
    const float* mask    = (const float*)d_in[1];
    const float* ln_in_g = (const float*)d_in[2];
    const float* ln_in_b = (const float*)d_in[3];
    const float* w_ag    = (const float*)d_in[4];
    const float* b_ag    = (const float*)d_in[5];
    const float* w_ap    = (const float*)d_in[6];
    const float* b_ap    = (const float*)d_in[7];
    const float* w_bg    = (const float*)d_in[8];
    const float* b_bg    = (const float*)d_in[9];
    const float* w_bp    = (const float*)d_in[10];
    const float* b_bp    = (const float*)d_in[11];
    const float* w_g     = (const float*)d_in[12];
    const float* b_g     = (const float*)d_in[13];
    const float* w_z     = (const float*)d_in[14];
    const float* b_z     = (const float*)d_in[15];
    const float* ln_o_g  = (const float*)d_in[16];
    const float* ln_o_b  = (const float*)d_in[17];
    float* out = (float*)d_out;
    u16* dz = (u16*)d_out;   // row m: gate bf16 at u16[0,128), zn bf16 at u16[128,256)

    char* ws = (char*)d_ws;
    const size_t SL = (size_t)MM * CCH * 2;  // 64MB per slot
    u16* xT   = (u16*)ws;
    u16* aT   = (u16*)(ws + SL);
    u16* bT   = (u16*)(ws + 2 * SL);
    u16* wbf  = (u16*)(ws + 3 * SL);                       // 192KB swizzled bf16 weights
    float* b2 = (float*)(ws + 3 * SL + 6 * 16384 * 2);     // 3KB folded biases

    k_prep<<<6, 256, 0, stream>>>(w_ag, w_ap, w_bg, w_bp, w_g, w_z,
                                  b_ag, b_ap, b_bg, b_bp, b_g, b_z,
                                  ln_in_g, ln_in_b, ln_o_g, ln_o_b, wbf, b2);
    k_ln<<<MM / 4, 256, 0, stream>>>(z, dz);
    k_proj<<<dim3(171, 2, 3), 256, 0, stream>>>(dz, mask, wbf, b2, aT, bT);
    k_tri<<<2048, 256, 0, stream>>>(aT, bT, xT);
    k_out<<<MM / 64, 256, 0, stream>>>(xT, wbf, b2, dz, out);
}

// Round 8
// 530.336 us; speedup vs baseline: 1.0139x; 1.0139x over previous
//
#include <hip/hip_runtime.h>

#define NN 512
#define CCH 128
#define MM (NN*NN)   // 262144

using f32x4  = __attribute__((ext_vector_type(4))) float;
using f32x2  = __attribute__((ext_vector_type(2))) float;
using bf16x8 = __attribute__((ext_vector_type(8))) short;
using u16x4  = __attribute__((ext_vector_type(4))) unsigned short;
using u32x2  = __attribute__((ext_vector_type(2))) unsigned int;
using u32x4  = __attribute__((ext_vector_type(4))) unsigned int;
typedef unsigned short u16;

__device__ __forceinline__ u16 f2bf(float f) {
    unsigned u = __builtin_bit_cast(unsigned, f);
    u += 0x7FFF + ((u >> 16) & 1);
    return (u16)(u >> 16);
}
__device__ __forceinline__ float bf2f(u16 h) {
    unsigned u = ((unsigned)h) << 16;
    return __builtin_bit_cast(float, u);
}
__device__ __forceinline__ unsigned pack2(float lo, float hi) {
    return (unsigned)f2bf(lo) | ((unsigned)f2bf(hi) << 16);
}
__device__ __forceinline__ float sigm(float x) { return 1.0f / (1.0f + __expf(-x)); }

__device__ __forceinline__ void gl_lds16(const void* g, void* l) {
    __builtin_amdgcn_global_load_lds(
        (const __attribute__((address_space(1))) void*)g,
        (__attribute__((address_space(3))) void*)l, 16, 0, 0);
}

// ---------------- k_prep: fold LN gamma/beta into bf16 weights + biases ----
// Weight rows stored CHUNK-SWIZZLED: logical 16B chunk q of row o lives at
// physical chunk (q ^ (o&7)).
__global__ __launch_bounds__(256) void k_prep(
    const float* __restrict__ w0, const float* __restrict__ w1,
    const float* __restrict__ w2, const float* __restrict__ w3,
    const float* __restrict__ w4, const float* __restrict__ w5,
    const float* __restrict__ b0, const float* __restrict__ b1,
    const float* __restrict__ b2, const float* __restrict__ b3,
    const float* __restrict__ b4, const float* __restrict__ b5,
    const float* __restrict__ gin, const float* __restrict__ bin,
    const float* __restrict__ gout, const float* __restrict__ bout,
    u16* __restrict__ wbf, float* __restrict__ bias2) {
    int mat = blockIdx.x;
    const float* W = mat==0?w0:mat==1?w1:mat==2?w2:mat==3?w3:mat==4?w4:w5;
    const float* B = mat==0?b0:mat==1?b1:mat==2?b2:mat==3?b3:mat==4?b4:b5;
    const float* G = (mat==5)? gout : gin;
    const float* Bt= (mat==5)? bout : bin;
    __shared__ float gs[CCH], bs[CCH];
    int tid = threadIdx.x;
    if (tid < CCH) { gs[tid] = G[tid]; bs[tid] = Bt[tid]; }
    __syncthreads();
    int o = tid >> 1, c0 = (tid & 1) * 64;
    const float* src = W + o * CCH + c0;
    char* dstrow = (char*)(wbf + mat * 16384) + o * 256;
    int key = o & 7;
    float dot = 0.f;
    #pragma unroll
    for (int q = 0; q < 16; ++q) {
        f32x4 v = *(const f32x4*)(src + q * 4);
        int c = c0 + q * 4;
        dot += bs[c]*v.x + bs[c+1]*v.y + bs[c+2]*v.z + bs[c+3]*v.w;
        u16x4 p;
        p.x = f2bf(v.x * gs[c]);     p.y = f2bf(v.y * gs[c+1]);
        p.z = f2bf(v.z * gs[c+2]);   p.w = f2bf(v.w * gs[c+3]);
        int chunk = (c0 >> 3) + (q >> 1);
        *(u16x4*)(dstrow + (((chunk ^ key)) << 4) + ((q & 1) << 3)) = p;
    }
    dot += __shfl_xor(dot, 1);
    if ((tid & 1) == 0) bias2[mat * CCH + o] = B[o] + dot;
}

// ---------------- k_ln: LN(z) -> zn (bf16, odd 256B halves of d_out) ------
__global__ __launch_bounds__(256) void k_ln(const float* __restrict__ z,
                                            u16* __restrict__ dz) {
    int tid = threadIdx.x;
    int w = tid >> 6, lane = tid & 63;
    long row = (long)blockIdx.x * 4 + w;
    f32x2 v = *(const f32x2*)(z + row * CCH + lane * 2);
    float s = v.x + v.y, s2 = v.x * v.x + v.y * v.y;
    #pragma unroll
    for (int off = 32; off; off >>= 1) {
        s  += __shfl_xor(s, off);
        s2 += __shfl_xor(s2, off);
    }
    float mu  = s * (1.0f / CCH);
    float var = fmaxf(s2 * (1.0f / CCH) - mu * mu, 0.f);
    float rs  = rsqrtf(var + 1e-5f);
    unsigned pk = pack2((v.x - mu) * rs, (v.y - mu) * rs);
    *(unsigned*)(dz + row * 256 + 128 + lane * 2) = pk;
}

// ---------------- k_proj: 8 m-tiles per block ------------------------------
// grid (512, 2, 3), x fastest => 6 quasi-sequential passes over dz (L3 reuse).
// Weights staged ONCE per block; inner m-loop barrier-free.
// mode 0: a-pair -> aT; mode 1: b-pair -> bT; mode 2: gate -> d_out row heads.
__global__ __launch_bounds__(256, 4) void k_proj(
    const u16* dz, const float* __restrict__ mask,
    const u16* __restrict__ wbf, const float* __restrict__ bias2,
    u16* __restrict__ aT, u16* __restrict__ bT) {
    __shared__ __align__(16) u16 w1s[8192];   // 16KB: 64 rows x 256B (swizzled)
    __shared__ __align__(16) u16 w2s[8192];
    int tid = threadIdx.x, w = tid >> 6, lane = tid & 63;
    int r = lane & 15, kq = lane >> 4;
    int ch = blockIdx.y, mode = blockIdx.z;
    int mat1 = (mode == 2) ? 4 : mode * 2;
    int mt0 = blockIdx.x * 8;

    const char* W1g = (const char*)wbf + (size_t)(mat1 * 16384 + ch * 64 * CCH) * 2;
    const char* W2g = (const char*)wbf + (size_t)((mat1 + 1) * 16384 + ch * 64 * CCH) * 2;
    #pragma unroll
    for (int it = 0; it < 4; ++it) {
        long off = (long)it * 4096 + tid * 16;
        gl_lds16(W1g + off, (char*)w1s + it * 4096 + w * 1024);
        if (mode < 2) gl_lds16(W2g + off, (char*)w2s + it * 4096 + w * 1024);
    }
    __syncthreads();

    if (mode < 2) {
        // hoisted loop invariants
        u16* dst = mode ? bT : aT;
        const float* B1 = bias2 + mat1 * CCH + ch * 64;
        const float* B2 = bias2 + (mat1 + 1) * CCH + ch * 64;
        float b1v[4], b2v[4];
        char* dptr[4];
        #pragma unroll
        for (int nt = 0; nt < 4; ++nt) {
            int cc = nt * 16 + r;
            b1v[nt] = B1[cc];
            b2v[nt] = B2[cc];
            dptr[nt] = (char*)(dst + (long)(ch * 64 + cc) * MM);
        }
        int i7 = (mt0 >> 3) & 7;                 // block-constant (8 tiles share mt>>3)
        int q = w * 2 + (kq >> 1);
        long boff_base = (long)((q ^ i7) << 4) + ((kq & 1) << 3);

        #pragma unroll 1
        for (int mt = mt0; mt < mt0 + 8; ++mt) {
            long m0 = (long)mt * 64;
            long mrow = m0 + w * 16 + r;
            bf16x8 av[4];
            #pragma unroll
            for (int kb = 0; kb < 4; ++kb)
                av[kb] = *(const bf16x8*)(dz + mrow * 256 + 128 + kb * 32 + kq * 8);
            f32x4 mkv = *(const f32x4*)(mask + m0 + w * 16 + kq * 4);

            f32x4 acc1[4], acc2[4];
            #pragma unroll
            for (int nt = 0; nt < 4; ++nt) { acc1[nt] = {0,0,0,0}; acc2[nt] = {0,0,0,0}; }
            #pragma unroll
            for (int nt = 0; nt < 4; ++nt) {
                int ol = nt * 16 + r;
                int key = ol & 7;
                const char* row1 = (const char*)w1s + ol * 256;
                const char* row2 = (const char*)w2s + ol * 256;
                #pragma unroll
                for (int kb = 0; kb < 4; ++kb) {
                    int ph = ((kb * 4 + kq) ^ key) << 4;
                    bf16x8 b1 = *(const bf16x8*)(row1 + ph);
                    bf16x8 b2 = *(const bf16x8*)(row2 + ph);
                    acc1[nt] = __builtin_amdgcn_mfma_f32_16x16x32_bf16(av[kb], b1, acc1[nt], 0, 0, 0);
                    acc2[nt] = __builtin_amdgcn_mfma_f32_16x16x32_bf16(av[kb], b2, acc2[nt], 0, 0, 0);
                }
            }
            long boff = m0 * 2 + boff_base;
            #pragma unroll
            for (int nt = 0; nt < 4; ++nt) {
                float v0 = mkv[0] * sigm(acc1[nt][0] + b1v[nt]) * (acc2[nt][0] + b2v[nt]);
                float v1 = mkv[1] * sigm(acc1[nt][1] + b1v[nt]) * (acc2[nt][1] + b2v[nt]);
                float v2 = mkv[2] * sigm(acc1[nt][2] + b1v[nt]) * (acc2[nt][2] + b2v[nt]);
                float v3 = mkv[3] * sigm(acc1[nt][3] + b1v[nt]) * (acc2[nt][3] + b2v[nt]);
                u32x2 pv; pv.x = pack2(v0, v1); pv.y = pack2(v2, v3);
                *(u32x2*)(dptr[nt] + boff) = pv;
            }
        }
    } else {
        // gate: mfma(W, zn): j-regs -> 4 consecutive c; col r -> m-row
        f32x4 bg[4];
        #pragma unroll
        for (int nt = 0; nt < 4; ++nt)
            bg[nt] = *(const f32x4*)(bias2 + 4 * CCH + ch * 64 + nt * 16 + kq * 4);
        int c0base = ch * 64 + kq * 4;

        #pragma unroll 1
        for (int mt = mt0; mt < mt0 + 8; ++mt) {
            long m0 = (long)mt * 64;
            long mrow = m0 + w * 16 + r;
            bf16x8 av[4];
            #pragma unroll
            for (int kb = 0; kb < 4; ++kb)
                av[kb] = *(const bf16x8*)(dz + mrow * 256 + 128 + kb * 32 + kq * 8);

            f32x4 acc[4];
            #pragma unroll
            for (int nt = 0; nt < 4; ++nt) acc[nt] = {0,0,0,0};
            #pragma unroll
            for (int nt = 0; nt < 4; ++nt) {
                int ol = nt * 16 + r;
                int key = ol & 7;
                const char* row1 = (const char*)w1s + ol * 256;
                #pragma unroll
                for (int kb = 0; kb < 4; ++kb) {
                    bf16x8 b1 = *(const bf16x8*)(row1 + (((kb * 4 + kq) ^ key) << 4));
                    acc[nt] = __builtin_amdgcn_mfma_f32_16x16x32_bf16(b1, av[kb], acc[nt], 0, 0, 0);
                }
            }
            #pragma unroll
            for (int nt = 0; nt < 4; ++nt) {
                u32x2 pv;
                pv.x = pack2(sigm(acc[nt][0] + bg[nt][0]), sigm(acc[nt][1] + bg[nt][1]));
                pv.y = pack2(sigm(acc[nt][2] + bg[nt][2]), sigm(acc[nt][3] + bg[nt][3]));
                *(u32x2*)((u16*)dz + mrow * 256 + c0base + nt * 16) = pv;
            }
        }
    }
}

// ---------------- k_tri: per-channel triangle GEMM, BK=64 ------------------
// swapped mfma: j-regs -> 4 consecutive j-columns -> packed 8B stores
__global__ __launch_bounds__(256, 4) void k_tri(const u16* __restrict__ aT,
                                                const u16* __restrict__ bT,
                                                u16* __restrict__ xT) {
    __shared__ __align__(16) u16 At[128 * 64];  // 16KB
    __shared__ __align__(16) u16 Bt[128 * 64];
    int tid = threadIdx.x;
    int w = tid >> 6, lane = tid & 63;
    int r = lane & 15, kq = lane >> 4;

    int L = blockIdx.x;
    int xcd = L & 7, idx = L >> 3;
    int c    = xcd + 8 * (idx >> 4);
    int tile = idx & 15;
    int ti = tile >> 2, tj = tile & 3;

    const char* abase = (const char*)(aT + (long)c * MM) + (long)(ti * 128) * 1024;
    const char* bbase = (const char*)(bT + (long)c * MM) + (long)(tj * 128) * 1024;
    int wm = w >> 1, wn = w & 1;

    f32x4 acc[4][4];
    #pragma unroll
    for (int a = 0; a < 4; ++a)
        #pragma unroll
        for (int bq = 0; bq < 4; ++bq) acc[a][bq] = {0.f,0.f,0.f,0.f};

    for (int ks = 0; ks < 8; ++ks) {
        const char* asrc = abase + ks * 128;
        const char* bsrc = bbase + ks * 128;
        #pragma unroll
        for (int it = 0; it < 4; ++it) {
            int u = it * 256 + tid;
            long goff = (long)(u >> 3) * 1024 + (u & 7) * 16;
            gl_lds16(asrc + goff, (char*)At + it * 4096 + w * 1024);
            gl_lds16(bsrc + goff, (char*)Bt + it * 4096 + w * 1024);
        }
        __syncthreads();

        #pragma unroll
        for (int kh = 0; kh < 2; ++kh) {
            bf16x8 af[4];
            #pragma unroll
            for (int mt = 0; mt < 4; ++mt) {
                int rowa = wm * 64 + mt * 16 + r;
                af[mt] = *(const bf16x8*)((const char*)At + rowa * 128 +
                                          (((kh * 4 + kq) ^ (r & 7)) << 4));
            }
            #pragma unroll
            for (int nt = 0; nt < 4; ++nt) {
                int rowb = wn * 64 + nt * 16 + r;
                bf16x8 bf = *(const bf16x8*)((const char*)Bt + rowb * 128 +
                                             (((kh * 4 + kq) ^ (r & 7)) << 4));
                #pragma unroll
                for (int mt = 0; mt < 4; ++mt)
                    acc[mt][nt] = __builtin_amdgcn_mfma_f32_16x16x32_bf16(bf, af[mt], acc[mt][nt], 0, 0, 0);
            }
        }
        __syncthreads();
    }

    // col r = i-row, j-regs = consecutive j
    u16* xbase = xT + (long)c * MM;
    int gi0 = ti * 128 + wm * 64;
    int gj0 = tj * 128 + wn * 64;
    #pragma unroll
    for (int mt = 0; mt < 4; ++mt) {
        long row = gi0 + mt * 16 + r;
        #pragma unroll
        for (int nt = 0; nt < 4; ++nt) {
            int col = gj0 + nt * 16 + kq * 4;
            u32x2 pv;
            pv.x = pack2(acc[mt][nt][0], acc[mt][nt][1]);
            pv.y = pack2(acc[mt][nt][2], acc[mt][nt][3]);
            *(u32x2*)(xbase + row * NN + col) = pv;
        }
    }
}

// ---------------- k_out: LN(x) @ w_z''^T + bias2_z, * gate -----------------
// swapped mfma: j-regs -> 4 consecutive c -> f32x4 stores
__global__ __launch_bounds__(256, 4) void k_out(const u16* __restrict__ xT,
                                                const u16* __restrict__ wbf,
                                                const float* __restrict__ bias2,
                                                const u16* gateB,
                                                float* __restrict__ outp) {
    __shared__ __align__(16) u16 xl[64 * 128];  // 16KB
    int tid = threadIdx.x, w = tid >> 6, lane = tid & 63;
    int r = lane & 15, kq = lane >> 4;
    long m0 = (long)blockIdx.x * 64;

    // transpose stage: xT[c][m] -> xl[m][c], 4 channels packed per u16x4
    {
        int cg = tid & 31, ms = tid >> 5;
        int c0 = cg * 4;
        const u16* base = xT + m0 + (long)ms * 8;
        bf16x8 v0 = *(const bf16x8*)(base + (long)(c0 + 0) * MM);
        bf16x8 v1 = *(const bf16x8*)(base + (long)(c0 + 1) * MM);
        bf16x8 v2 = *(const bf16x8*)(base + (long)(c0 + 2) * MM);
        bf16x8 v3 = *(const bf16x8*)(base + (long)(c0 + 3) * MM);
        #pragma unroll
        for (int e = 0; e < 8; ++e) {
            int m = ms * 8 + e;
            u16x4 t;
            t.x = (u16)v0[e]; t.y = (u16)v1[e]; t.z = (u16)v2[e]; t.w = (u16)v3[e];
            *(u16x4*)((char*)xl + m * 256 + ((c0 * 2) ^ ((m & 15) << 4))) = t;
        }
    }
    __syncthreads();

    // A-frags as u32 pairs + LN stats via mask/shift decode
    int mlr = w * 16 + r;
    int swm = (mlr & 15) << 4;
    u32x4 avu[4];
    float s = 0.f, s2 = 0.f;
    #pragma unroll
    for (int kb = 0; kb < 4; ++kb) {
        avu[kb] = *(const u32x4*)((const char*)xl + mlr * 256 + ((kb * 64 + kq * 16) ^ swm));
        #pragma unroll
        for (int p = 0; p < 4; ++p) {
            unsigned u = avu[kb][p];
            float flo = __builtin_bit_cast(float, u << 16);
            float fhi = __builtin_bit_cast(float, u & 0xFFFF0000u);
            s += flo + fhi;
            s2 = fmaf(flo, flo, s2);
            s2 = fmaf(fhi, fhi, s2);
        }
    }
    s  += __shfl_xor(s, 16);  s  += __shfl_xor(s, 32);
    s2 += __shfl_xor(s2, 16); s2 += __shfl_xor(s2, 32);
    float mu = s * (1.0f / CCH);
    float var = fmaxf(s2 * (1.0f / CCH) - mu * mu, 0.f);
    float rs = rsqrtf(var + 1e-5f);
    float nmu = -mu * rs;
    bf16x8 av[4];
    #pragma unroll
    for (int kb = 0; kb < 4; ++kb) {
        u32x4 o;
        #pragma unroll
        for (int p = 0; p < 4; ++p) {
            unsigned u = avu[kb][p];
            float flo = __builtin_bit_cast(float, u << 16);
            float fhi = __builtin_bit_cast(float, u & 0xFFFF0000u);
            o[p] = pack2(fmaf(flo, rs, nmu), fmaf(fhi, rs, nmu));
        }
        av[kb] = __builtin_bit_cast(bf16x8, o);
    }

    // gate preload (gateB aliases outp rows of THIS block only)
    long m = m0 + w * 16 + r;
    u16x4 gvu[8];
    #pragma unroll
    for (int nt = 0; nt < 8; ++nt)
        gvu[nt] = *(const u16x4*)(gateB + m * 256 + nt * 16 + kq * 4);

    // swapped MFMA vs w_z'' (global reads, chunk-swizzled layout)
    const char* Wz = (const char*)(wbf + 5 * 16384);
    f32x4 acc[8];
    #pragma unroll
    for (int nt = 0; nt < 8; ++nt) acc[nt] = {0,0,0,0};
    #pragma unroll
    for (int nt = 0; nt < 8; ++nt) {
        int ol = nt * 16 + r;
        int key = ol & 7;
        const char* row = Wz + ol * 256;
        #pragma unroll
        for (int kb = 0; kb < 4; ++kb) {
            bf16x8 bw = *(const bf16x8*)(row + (((kb * 4 + kq) ^ key) << 4));
            acc[nt] = __builtin_amdgcn_mfma_f32_16x16x32_bf16(bw, av[kb], acc[nt], 0, 0, 0);
        }
    }

    __syncthreads();   // ALL gate loads done before any aliasing store

    const float* b2z = bias2 + 5 * CCH;
    #pragma unroll
    for (int nt = 0; nt < 8; ++nt) {
        int c0 = nt * 16 + kq * 4;
        f32x4 bb = *(const f32x4*)(b2z + c0);
        f32x4 o;
        #pragma unroll
        for (int j = 0; j < 4; ++j)
            o[j] = (acc[nt][j] + bb[j]) * bf2f(gvu[nt][j]);
        *(f32x4*)(outp + m * CCH + c0) = o;
    }
}

extern "C" void kernel_launch(void* const* d_in, const int* in_sizes, int n_in,
                              void* d_out, int out_size, void* d_ws, size_t ws_size,
                              hipStream_t stream) {
    const float* z       = (const float*)d_in[0];
    const float* mask    = (const float*)d_in[1];
    const float* ln_in_g = (const float*)d_in[2];
    const float* ln_in_b = (const float*)d_in[3];
    const float* w_ag    = (const float*)d_in[4];
    const float* b_ag    = (const float*)d_in[5];
    const float* w_ap    = (const float*)d_in[6];
    const float* b_ap    = (const float*)d_in[7];
    const float* w_bg    = (const float*)d_in[8];
    const float* b_bg    = (const float*)d_in[9];
    const float* w_bp    = (const float*)d_in[10];
    const float* b_bp    = (const float*)d_in[11];
    const float* w_g     = (const float*)d_in[12];
    const float* b_g     = (const float*)d_in[13];
    const float* w_z     = (const float*)d_in[14];
    const float* b_z     = (const float*)d_in[15];
    const float* ln_o_g  = (const float*)d_in[16];
    const float* ln_o_b  = (const float*)d_in[17];
    float* out = (float*)d_out;
    u16* dz = (u16*)d_out;   // row m: gate bf16 at u16[0,128), zn bf16 at u16[128,256)

    char* ws = (char*)d_ws;
    const size_t SL = (size_t)MM * CCH * 2;  // 64MB per slot
    u16* xT   = (u16*)ws;
    u16* aT   = (u16*)(ws + SL);
    u16* bT   = (u16*)(ws + 2 * SL);
    u16* wbf  = (u16*)(ws + 3 * SL);                       // 192KB swizzled bf16 weights
    float* b2 = (float*)(ws + 3 * SL + 6 * 16384 * 2);     // 3KB folded biases

    k_prep<<<6, 256, 0, stream>>>(w_ag, w_ap, w_bg, w_bp, w_g, w_z,
                                  b_ag, b_ap, b_bg, b_bp, b_g, b_z,
                                  ln_in_g, ln_in_b, ln_o_g, ln_o_b, wbf, b2);
    k_ln<<<MM / 4, 256, 0, stream>>>(z, dz);
    k_proj<<<dim3(512, 2, 3), 256, 0, stream>>>(dz, mask, wbf, b2, aT, bT);
    k_tri<<<2048, 256, 0, stream>>>(aT, bT, xT);
    k_out<<<MM / 64, 256, 0, stream>>>(xT, wbf, b2, dz, out);
}

// Round 9
// 346.109 us; speedup vs baseline: 1.5536x; 1.5323x over previous
//
#include <hip/hip_runtime.h>

#define NN 512
#define CCH 128
#define MM (NN*NN)   // 262144

using f32x4  = __attribute__((ext_vector_type(4))) float;
using f32x2  = __attribute__((ext_vector_type(2))) float;
using bf16x8 = __attribute__((ext_vector_type(8))) short;
using u16x4  = __attribute__((ext_vector_type(4))) unsigned short;
using u32x2  = __attribute__((ext_vector_type(2))) unsigned int;
using u32x4  = __attribute__((ext_vector_type(4))) unsigned int;
typedef unsigned short u16;

__device__ __forceinline__ u16 f2bf(float f) {
    unsigned u = __builtin_bit_cast(unsigned, f);
    u += 0x7FFF + ((u >> 16) & 1);
    return (u16)(u >> 16);
}
__device__ __forceinline__ float bf2f(u16 h) {
    unsigned u = ((unsigned)h) << 16;
    return __builtin_bit_cast(float, u);
}
__device__ __forceinline__ unsigned pack2(float lo, float hi) {
    return (unsigned)f2bf(lo) | ((unsigned)f2bf(hi) << 16);
}
__device__ __forceinline__ float sigm(float x) { return 1.0f / (1.0f + __expf(-x)); }

__device__ __forceinline__ void gl_lds16(const void* g, void* l) {
    __builtin_amdgcn_global_load_lds(
        (const __attribute__((address_space(1))) void*)g,
        (__attribute__((address_space(3))) void*)l, 16, 0, 0);
}

// ---------------- k_prep: fold LN gamma/beta into bf16 weights + biases ----
// Weight rows stored CHUNK-SWIZZLED: logical 16B chunk q of row o lives at
// physical chunk (q ^ (o&7)).
__global__ __launch_bounds__(256) void k_prep(
    const float* __restrict__ w0, const float* __restrict__ w1,
    const float* __restrict__ w2, const float* __restrict__ w3,
    const float* __restrict__ w4, const float* __restrict__ w5,
    const float* __restrict__ b0, const float* __restrict__ b1,
    const float* __restrict__ b2, const float* __restrict__ b3,
    const float* __restrict__ b4, const float* __restrict__ b5,
    const float* __restrict__ gin, const float* __restrict__ bin,
    const float* __restrict__ gout, const float* __restrict__ bout,
    u16* __restrict__ wbf, float* __restrict__ bias2) {
    int mat = blockIdx.x;
    const float* W = mat==0?w0:mat==1?w1:mat==2?w2:mat==3?w3:mat==4?w4:w5;
    const float* B = mat==0?b0:mat==1?b1:mat==2?b2:mat==3?b3:mat==4?b4:b5;
    const float* G = (mat==5)? gout : gin;
    const float* Bt= (mat==5)? bout : bin;
    __shared__ float gs[CCH], bs[CCH];
    int tid = threadIdx.x;
    if (tid < CCH) { gs[tid] = G[tid]; bs[tid] = Bt[tid]; }
    __syncthreads();
    int o = tid >> 1, c0 = (tid & 1) * 64;
    const float* src = W + o * CCH + c0;
    char* dstrow = (char*)(wbf + mat * 16384) + o * 256;
    int key = o & 7;
    float dot = 0.f;
    #pragma unroll
    for (int q = 0; q < 16; ++q) {
        f32x4 v = *(const f32x4*)(src + q * 4);
        int c = c0 + q * 4;
        dot += bs[c]*v.x + bs[c+1]*v.y + bs[c+2]*v.z + bs[c+3]*v.w;
        u16x4 p;
        p.x = f2bf(v.x * gs[c]);     p.y = f2bf(v.y * gs[c+1]);
        p.z = f2bf(v.z * gs[c+2]);   p.w = f2bf(v.w * gs[c+3]);
        int chunk = (c0 >> 3) + (q >> 1);
        *(u16x4*)(dstrow + (((chunk ^ key)) << 4) + ((q & 1) << 3)) = p;
    }
    dot += __shfl_xor(dot, 1);
    if ((tid & 1) == 0) bias2[mat * CCH + o] = B[o] + dot;
}

// ---------------- k_ln: LN(z) -> zn (dense bf16 [m][128] in ws) ------------
__global__ __launch_bounds__(256) void k_ln(const float* __restrict__ z,
                                            u16* __restrict__ zn) {
    int tid = threadIdx.x;
    int w = tid >> 6, lane = tid & 63;
    long row = (long)blockIdx.x * 4 + w;
    f32x2 v = *(const f32x2*)(z + row * CCH + lane * 2);
    float s = v.x + v.y, s2 = v.x * v.x + v.y * v.y;
    #pragma unroll
    for (int off = 32; off; off >>= 1) {
        s  += __shfl_xor(s, off);
        s2 += __shfl_xor(s2, off);
    }
    float mu  = s * (1.0f / CCH);
    float var = fmaxf(s2 * (1.0f / CCH) - mu * mu, 0.f);
    float rs  = rsqrtf(var + 1e-5f);
    unsigned pk = pack2((v.x - mu) * rs, (v.y - mu) * rs);
    *(unsigned*)(zn + row * CCH + lane * 2) = pk;
}

// ---------------- k_proj: full-channel blocks, 3 passes --------------------
// grid (4096, 3), x fastest => 3 quasi-sequential passes over zn (L3 reuse).
// Each block: 64 m-rows, full 128 out channels, weights (1 or 2 matrices)
// staged once into LDS.
// mode 0: a-pair -> aT; mode 1: b-pair -> bT; mode 2: gate -> d_out row heads.
__global__ __launch_bounds__(256) void k_proj(
    const u16* __restrict__ zn, const float* __restrict__ mask,
    const u16* __restrict__ wbf, const float* __restrict__ bias2,
    u16* __restrict__ aT, u16* __restrict__ bT, u16* gateB) {
    __shared__ __align__(16) u16 w1s[16384];   // 32KB: 128 rows x 256B (swizzled)
    __shared__ __align__(16) u16 w2s[16384];
    int tid = threadIdx.x, w = tid >> 6, lane = tid & 63;
    int r = lane & 15, kq = lane >> 4;
    int mode = blockIdx.y;
    int mat1 = (mode == 2) ? 4 : mode * 2;
    long m0 = (long)blockIdx.x * 64;

    const char* W1g = (const char*)(wbf + mat1 * 16384);
    const char* W2g = (const char*)(wbf + (mat1 + 1) * 16384);
    #pragma unroll
    for (int it = 0; it < 8; ++it) {
        long off = (long)it * 4096 + tid * 16;
        gl_lds16(W1g + off, (char*)w1s + it * 4096 + w * 1024);
        if (mode < 2) gl_lds16(W2g + off, (char*)w2s + it * 4096 + w * 1024);
    }

    // A-fragments from zn (global, dense bf16)
    bf16x8 av[4];
    long mrow = m0 + w * 16 + r;
    #pragma unroll
    for (int kb = 0; kb < 4; ++kb)
        av[kb] = *(const bf16x8*)(zn + mrow * CCH + kb * 32 + kq * 8);

    f32x4 mkv = {1.f, 1.f, 1.f, 1.f};
    if (mode < 2) mkv = *(const f32x4*)(mask + m0 + w * 16 + kq * 4);

    __syncthreads();

    if (mode < 2) {
        // mfma(zn, W): j-regs -> 4 consecutive m; col r -> out channel
        u16* dst = mode ? bT : aT;
        const float* B1 = bias2 + mat1 * CCH;
        const float* B2 = bias2 + (mat1 + 1) * CCH;
        int i7 = (int)((blockIdx.x >> 3) & 7);
        int q = w * 2 + (kq >> 1);
        long boff = m0 * 2 + (long)((q ^ i7) << 4) + ((kq & 1) << 3);

        f32x4 acc1[8], acc2[8];
        #pragma unroll
        for (int nt = 0; nt < 8; ++nt) { acc1[nt] = {0,0,0,0}; acc2[nt] = {0,0,0,0}; }
        #pragma unroll
        for (int nt = 0; nt < 8; ++nt) {
            int ol = nt * 16 + r;
            int key = ol & 7;
            const char* row1 = (const char*)w1s + ol * 256;
            const char* row2 = (const char*)w2s + ol * 256;
            #pragma unroll
            for (int kb = 0; kb < 4; ++kb) {
                int ph = ((kb * 4 + kq) ^ key) << 4;
                bf16x8 b1 = *(const bf16x8*)(row1 + ph);
                bf16x8 b2 = *(const bf16x8*)(row2 + ph);
                acc1[nt] = __builtin_amdgcn_mfma_f32_16x16x32_bf16(av[kb], b1, acc1[nt], 0, 0, 0);
                acc2[nt] = __builtin_amdgcn_mfma_f32_16x16x32_bf16(av[kb], b2, acc2[nt], 0, 0, 0);
            }
        }
        #pragma unroll
        for (int nt = 0; nt < 8; ++nt) {
            int cc = nt * 16 + r;
            float b1v = B1[cc], b2v = B2[cc];
            float v0 = mkv[0] * sigm(acc1[nt][0] + b1v) * (acc2[nt][0] + b2v);
            float v1 = mkv[1] * sigm(acc1[nt][1] + b1v) * (acc2[nt][1] + b2v);
            float v2 = mkv[2] * sigm(acc1[nt][2] + b1v) * (acc2[nt][2] + b2v);
            float v3 = mkv[3] * sigm(acc1[nt][3] + b1v) * (acc2[nt][3] + b2v);
            u32x2 pv; pv.x = pack2(v0, v1); pv.y = pack2(v2, v3);
            *(u32x2*)((char*)dst + ((long)cc << 19) + boff) = pv;
        }
    } else {
        // gate: mfma(W, zn): j-regs -> 4 consecutive c; col r -> m-row
        f32x4 acc[8];
        #pragma unroll
        for (int nt = 0; nt < 8; ++nt) acc[nt] = {0,0,0,0};
        #pragma unroll
        for (int nt = 0; nt < 8; ++nt) {
            int ol = nt * 16 + r;
            int key = ol & 7;
            const char* row1 = (const char*)w1s + ol * 256;
            #pragma unroll
            for (int kb = 0; kb < 4; ++kb) {
                bf16x8 b1 = *(const bf16x8*)(row1 + (((kb * 4 + kq) ^ key) << 4));
                acc[nt] = __builtin_amdgcn_mfma_f32_16x16x32_bf16(b1, av[kb], acc[nt], 0, 0, 0);
            }
        }
        long m = m0 + w * 16 + r;
        #pragma unroll
        for (int nt = 0; nt < 8; ++nt) {
            int c0 = nt * 16 + kq * 4;
            f32x4 bg = *(const f32x4*)(bias2 + 4 * CCH + c0);
            u32x2 pv;
            pv.x = pack2(sigm(acc[nt][0] + bg[0]), sigm(acc[nt][1] + bg[1]));
            pv.y = pack2(sigm(acc[nt][2] + bg[2]), sigm(acc[nt][3] + bg[3]));
            *(u32x2*)(gateB + m * 256 + c0) = pv;
        }
    }
}

// ---------------- k_tri: per-channel triangle GEMM, BK=64 ------------------
// swapped mfma: j-regs -> 4 consecutive j-columns -> packed 8B stores
__global__ __launch_bounds__(256, 4) void k_tri(const u16* __restrict__ aT,
                                                const u16* __restrict__ bT,
                                                u16* __restrict__ xT) {
    __shared__ __align__(16) u16 At[128 * 64];  // 16KB
    __shared__ __align__(16) u16 Bt[128 * 64];
    int tid = threadIdx.x;
    int w = tid >> 6, lane = tid & 63;
    int r = lane & 15, kq = lane >> 4;

    int L = blockIdx.x;
    int xcd = L & 7, idx = L >> 3;
    int c    = xcd + 8 * (idx >> 4);
    int tile = idx & 15;
    int ti = tile >> 2, tj = tile & 3;

    const char* abase = (const char*)(aT + (long)c * MM) + (long)(ti * 128) * 1024;
    const char* bbase = (const char*)(bT + (long)c * MM) + (long)(tj * 128) * 1024;
    int wm = w >> 1, wn = w & 1;

    f32x4 acc[4][4];
    #pragma unroll
    for (int a = 0; a < 4; ++a)
        #pragma unroll
        for (int bq = 0; bq < 4; ++bq) acc[a][bq] = {0.f,0.f,0.f,0.f};

    for (int ks = 0; ks < 8; ++ks) {
        const char* asrc = abase + ks * 128;
        const char* bsrc = bbase + ks * 128;
        #pragma unroll
        for (int it = 0; it < 4; ++it) {
            int u = it * 256 + tid;
            long goff = (long)(u >> 3) * 1024 + (u & 7) * 16;
            gl_lds16(asrc + goff, (char*)At + it * 4096 + w * 1024);
            gl_lds16(bsrc + goff, (char*)Bt + it * 4096 + w * 1024);
        }
        __syncthreads();

        #pragma unroll
        for (int kh = 0; kh < 2; ++kh) {
            bf16x8 af[4];
            #pragma unroll
            for (int mt = 0; mt < 4; ++mt) {
                int rowa = wm * 64 + mt * 16 + r;
                af[mt] = *(const bf16x8*)((const char*)At + rowa * 128 +
                                          (((kh * 4 + kq) ^ (r & 7)) << 4));
            }
            #pragma unroll
            for (int nt = 0; nt < 4; ++nt) {
                int rowb = wn * 64 + nt * 16 + r;
                bf16x8 bf = *(const bf16x8*)((const char*)Bt + rowb * 128 +
                                             (((kh * 4 + kq) ^ (r & 7)) << 4));
                #pragma unroll
                for (int mt = 0; mt < 4; ++mt)
                    acc[mt][nt] = __builtin_amdgcn_mfma_f32_16x16x32_bf16(bf, af[mt], acc[mt][nt], 0, 0, 0);
            }
        }
        __syncthreads();
    }

    // col r = i-row, j-regs = consecutive j
    u16* xbase = xT + (long)c * MM;
    int gi0 = ti * 128 + wm * 64;
    int gj0 = tj * 128 + wn * 64;
    #pragma unroll
    for (int mt = 0; mt < 4; ++mt) {
        long row = gi0 + mt * 16 + r;
        #pragma unroll
        for (int nt = 0; nt < 4; ++nt) {
            int col = gj0 + nt * 16 + kq * 4;
            u32x2 pv;
            pv.x = pack2(acc[mt][nt][0], acc[mt][nt][1]);
            pv.y = pack2(acc[mt][nt][2], acc[mt][nt][3]);
            *(u32x2*)(xbase + row * NN + col) = pv;
        }
    }
}

// ---------------- k_out: LN(x) @ w_z''^T + bias2_z, * gate -----------------
// swapped mfma: j-regs -> 4 consecutive c -> f32x4 stores
__global__ __launch_bounds__(256, 4) void k_out(const u16* __restrict__ xT,
                                                const u16* __restrict__ wbf,
                                                const float* __restrict__ bias2,
                                                const u16* gateB,
                                                float* __restrict__ outp) {
    __shared__ __align__(16) u16 xl[64 * 128];  // 16KB
    int tid = threadIdx.x, w = tid >> 6, lane = tid & 63;
    int r = lane & 15, kq = lane >> 4;
    long m0 = (long)blockIdx.x * 64;

    // transpose stage: xT[c][m] -> xl[m][c], 4 channels packed per u16x4
    {
        int cg = tid & 31, ms = tid >> 5;
        int c0 = cg * 4;
        const u16* base = xT + m0 + (long)ms * 8;
        bf16x8 v0 = *(const bf16x8*)(base + (long)(c0 + 0) * MM);
        bf16x8 v1 = *(const bf16x8*)(base + (long)(c0 + 1) * MM);
        bf16x8 v2 = *(const bf16x8*)(base + (long)(c0 + 2) * MM);
        bf16x8 v3 = *(const bf16x8*)(base + (long)(c0 + 3) * MM);
        #pragma unroll
        for (int e = 0; e < 8; ++e) {
            int m = ms * 8 + e;
            u16x4 t;
            t.x = (u16)v0[e]; t.y = (u16)v1[e]; t.z = (u16)v2[e]; t.w = (u16)v3[e];
            *(u16x4*)((char*)xl + m * 256 + ((c0 * 2) ^ ((m & 15) << 4))) = t;
        }
    }
    __syncthreads();

    // A-frags as u32 pairs + LN stats via mask/shift decode
    int mlr = w * 16 + r;
    int swm = (mlr & 15) << 4;
    u32x4 avu[4];
    float s = 0.f, s2 = 0.f;
    #pragma unroll
    for (int kb = 0; kb < 4; ++kb) {
        avu[kb] = *(const u32x4*)((const char*)xl + mlr * 256 + ((kb * 64 + kq * 16) ^ swm));
        #pragma unroll
        for (int p = 0; p < 4; ++p) {
            unsigned u = avu[kb][p];
            float flo = __builtin_bit_cast(float, u << 16);
            float fhi = __builtin_bit_cast(float, u & 0xFFFF0000u);
            s += flo + fhi;
            s2 = fmaf(flo, flo, s2);
            s2 = fmaf(fhi, fhi, s2);
        }
    }
    s  += __shfl_xor(s, 16);  s  += __shfl_xor(s, 32);
    s2 += __shfl_xor(s2, 16); s2 += __shfl_xor(s2, 32);
    float mu = s * (1.0f / CCH);
    float var = fmaxf(s2 * (1.0f / CCH) - mu * mu, 0.f);
    float rs = rsqrtf(var + 1e-5f);
    float nmu = -mu * rs;
    bf16x8 av[4];
    #pragma unroll
    for (int kb = 0; kb < 4; ++kb) {
        u32x4 o;
        #pragma unroll
        for (int p = 0; p < 4; ++p) {
            unsigned u = avu[kb][p];
            float flo = __builtin_bit_cast(float, u << 16);
            float fhi = __builtin_bit_cast(float, u & 0xFFFF0000u);
            o[p] = pack2(fmaf(flo, rs, nmu), fmaf(fhi, rs, nmu));
        }
        av[kb] = __builtin_bit_cast(bf16x8, o);
    }

    // gate preload (gateB aliases outp rows of THIS block only)
    long m = m0 + w * 16 + r;
    u16x4 gvu[8];
    #pragma unroll
    for (int nt = 0; nt < 8; ++nt)
        gvu[nt] = *(const u16x4*)(gateB + m * 256 + nt * 16 + kq * 4);

    // swapped MFMA vs w_z'' (global reads, chunk-swizzled layout)
    const char* Wz = (const char*)(wbf + 5 * 16384);
    f32x4 acc[8];
    #pragma unroll
    for (int nt = 0; nt < 8; ++nt) acc[nt] = {0,0,0,0};
    #pragma unroll
    for (int nt = 0; nt < 8; ++nt) {
        int ol = nt * 16 + r;
        int key = ol & 7;
        const char* row = Wz + ol * 256;
        #pragma unroll
        for (int kb = 0; kb < 4; ++kb) {
            bf16x8 bw = *(const bf16x8*)(row + (((kb * 4 + kq) ^ key) << 4));
            acc[nt] = __builtin_amdgcn_mfma_f32_16x16x32_bf16(bw, av[kb], acc[nt], 0, 0, 0);
        }
    }

    __syncthreads();   // ALL gate loads done before any aliasing store

    const float* b2z = bias2 + 5 * CCH;
    #pragma unroll
    for (int nt = 0; nt < 8; ++nt) {
        int c0 = nt * 16 + kq * 4;
        f32x4 bb = *(const f32x4*)(b2z + c0);
        f32x4 o;
        #pragma unroll
        for (int j = 0; j < 4; ++j)
            o[j] = (acc[nt][j] + bb[j]) * bf2f(gvu[nt][j]);
        *(f32x4*)(outp + m * CCH + c0) = o;
    }
}

extern "C" void kernel_launch(void* const* d_in, const int* in_sizes, int n_in,
                              void* d_out, int out_size, void* d_ws, size_t ws_size,
                              hipStream_t stream) {
    const float* z       = (const float*)d_in[0];
    const float* mask    = (const float*)d_in[1];
    const float* ln_in_g = (const float*)d_in[2];
    const float* ln_in_b = (const float*)d_in[3];
    const float* w_ag    = (const float*)d_in[4];
    const float* b_ag    = (const float*)d_in[5];
    const float* w_ap    = (const float*)d_in[6];
    const float* b_ap    = (const float*)d_in[7];
    const float* w_bg    = (const float*)d_in[8];
    const float* b_bg    = (const float*)d_in[9];
    const float* w_bp    = (const float*)d_in[10];
    const float* b_bp    = (const float*)d_in[11];
    const float* w_g     = (const float*)d_in[12];
    const float* b_g     = (const float*)d_in[13];
    const float* w_z     = (const float*)d_in[14];
    const float* b_z     = (const float*)d_in[15];
    const float* ln_o_g  = (const float*)d_in[16];
    const float* ln_o_b  = (const float*)d_in[17];
    float* out = (float*)d_out;
    u16* gateB = (u16*)d_out;   // gate bf16 in first 256B of each 512B d_out row

    char* ws = (char*)d_ws;
    const size_t SL = (size_t)MM * CCH * 2;  // 64MB per slot
    u16* xT   = (u16*)ws;
    u16* aT   = (u16*)(ws + SL);
    u16* bT   = (u16*)(ws + 2 * SL);
    u16* zn   = (u16*)(ws + 3 * SL);
    u16* wbf  = (u16*)(ws + 4 * SL);                       // 192KB swizzled bf16 weights
    float* b2 = (float*)(ws + 4 * SL + 6 * 16384 * 2);     // 3KB folded biases

    k_prep<<<6, 256, 0, stream>>>(w_ag, w_ap, w_bg, w_bp, w_g, w_z,
                                  b_ag, b_ap, b_bg, b_bp, b_g, b_z,
                                  ln_in_g, ln_in_b, ln_o_g, ln_o_b, wbf, b2);
    k_ln<<<MM / 4, 256, 0, stream>>>(z, zn);
    k_proj<<<dim3(MM / 64, 3), 256, 0, stream>>>(zn, mask, wbf, b2, aT, bT, gateB);
    k_tri<<<2048, 256, 0, stream>>>(aT, bT, xT);
    k_out<<<MM / 64, 256, 0, stream>>>(xT, wbf, b2, gateB, out);
}

// Round 10
// 332.437 us; speedup vs baseline: 1.6175x; 1.0411x over previous
//
#include <hip/hip_runtime.h>

#define NN 512
#define CCH 128
#define MM (NN*NN)   // 262144

using f32x4  = __attribute__((ext_vector_type(4))) float;
using f32x2  = __attribute__((ext_vector_type(2))) float;
using bf16x8 = __attribute__((ext_vector_type(8))) short;
using u16x4  = __attribute__((ext_vector_type(4))) unsigned short;
using u32x2  = __attribute__((ext_vector_type(2))) unsigned int;
using u32x4  = __attribute__((ext_vector_type(4))) unsigned int;
typedef unsigned short u16;

__device__ __forceinline__ u16 f2bf(float f) {
    unsigned u = __builtin_bit_cast(unsigned, f);
    u += 0x7FFF + ((u >> 16) & 1);
    return (u16)(u >> 16);
}
__device__ __forceinline__ float bf2f(u16 h) {
    unsigned u = ((unsigned)h) << 16;
    return __builtin_bit_cast(float, u);
}
__device__ __forceinline__ unsigned pack2(float lo, float hi) {
    return (unsigned)f2bf(lo) | ((unsigned)f2bf(hi) << 16);
}
__device__ __forceinline__ float sigm(float x) { return 1.0f / (1.0f + __expf(-x)); }

__device__ __forceinline__ void gl_lds16(const void* g, void* l) {
    __builtin_amdgcn_global_load_lds(
        (const __attribute__((address_space(1))) void*)g,
        (__attribute__((address_space(3))) void*)l, 16, 0, 0);
}

// ---------------- k_prep: fold LN gamma/beta into bf16 weights + biases ----
// Weight rows stored CHUNK-SWIZZLED: logical 16B chunk q of row o lives at
// physical chunk (q ^ (o&7)).
__global__ __launch_bounds__(256) void k_prep(
    const float* __restrict__ w0, const float* __restrict__ w1,
    const float* __restrict__ w2, const float* __restrict__ w3,
    const float* __restrict__ w4, const float* __restrict__ w5,
    const float* __restrict__ b0, const float* __restrict__ b1,
    const float* __restrict__ b2, const float* __restrict__ b3,
    const float* __restrict__ b4, const float* __restrict__ b5,
    const float* __restrict__ gin, const float* __restrict__ bin,
    const float* __restrict__ gout, const float* __restrict__ bout,
    u16* __restrict__ wbf, float* __restrict__ bias2) {
    int mat = blockIdx.x;
    const float* W = mat==0?w0:mat==1?w1:mat==2?w2:mat==3?w3:mat==4?w4:w5;
    const float* B = mat==0?b0:mat==1?b1:mat==2?b2:mat==3?b3:mat==4?b4:b5;
    const float* G = (mat==5)? gout : gin;
    const float* Bt= (mat==5)? bout : bin;
    __shared__ float gs[CCH], bs[CCH];
    int tid = threadIdx.x;
    if (tid < CCH) { gs[tid] = G[tid]; bs[tid] = Bt[tid]; }
    __syncthreads();
    int o = tid >> 1, c0 = (tid & 1) * 64;
    const float* src = W + o * CCH + c0;
    char* dstrow = (char*)(wbf + mat * 16384) + o * 256;
    int key = o & 7;
    float dot = 0.f;
    #pragma unroll
    for (int q = 0; q < 16; ++q) {
        f32x4 v = *(const f32x4*)(src + q * 4);
        int c = c0 + q * 4;
        dot += bs[c]*v.x + bs[c+1]*v.y + bs[c+2]*v.z + bs[c+3]*v.w;
        u16x4 p;
        p.x = f2bf(v.x * gs[c]);     p.y = f2bf(v.y * gs[c+1]);
        p.z = f2bf(v.z * gs[c+2]);   p.w = f2bf(v.w * gs[c+3]);
        int chunk = (c0 >> 3) + (q >> 1);
        *(u16x4*)(dstrow + (((chunk ^ key)) << 4) + ((q & 1) << 3)) = p;
    }
    dot += __shfl_xor(dot, 1);
    if ((tid & 1) == 0) bias2[mat * CCH + o] = B[o] + dot;
}

// ---------------- k_ln: LN(z) -> zn (dense bf16 [m][128] in ws) ------------
__global__ __launch_bounds__(256) void k_ln(const float* __restrict__ z,
                                            u16* __restrict__ zn) {
    int tid = threadIdx.x;
    int w = tid >> 6, lane = tid & 63;
    long row = (long)blockIdx.x * 4 + w;
    f32x2 v = *(const f32x2*)(z + row * CCH + lane * 2);
    float s = v.x + v.y, s2 = v.x * v.x + v.y * v.y;
    #pragma unroll
    for (int off = 32; off; off >>= 1) {
        s  += __shfl_xor(s, off);
        s2 += __shfl_xor(s2, off);
    }
    float mu  = s * (1.0f / CCH);
    float var = fmaxf(s2 * (1.0f / CCH) - mu * mu, 0.f);
    float rs  = rsqrtf(var + 1e-5f);
    unsigned pk = pack2((v.x - mu) * rs, (v.y - mu) * rs);
    *(unsigned*)(zn + row * CCH + lane * 2) = pk;
}

// ---------------- k_proj: full-channel blocks, 3 passes --------------------
// grid (4096, 3). mode 0: a-pair -> aT; mode 1: b-pair -> bT; mode 2: gate.
// Pair epilogue: LDS gather -> FULL-128B-LINE stores (8 lines per inst).
__global__ __launch_bounds__(256) void k_proj(
    const u16* __restrict__ zn, const float* __restrict__ mask,
    const u16* __restrict__ wbf, const float* __restrict__ bias2,
    u16* __restrict__ aT, u16* __restrict__ bT, u16* gateB) {
    __shared__ __align__(16) u16 w1s[16384];   // 32KB: 128 rows x 256B (swizzled)
    __shared__ __align__(16) u16 w2s[16384];
    int tid = threadIdx.x, w = tid >> 6, lane = tid & 63;
    int r = lane & 15, kq = lane >> 4;
    int mode = blockIdx.y;
    int mat1 = (mode == 2) ? 4 : mode * 2;
    long m0 = (long)blockIdx.x * 64;

    const char* W1g = (const char*)(wbf + mat1 * 16384);
    const char* W2g = (const char*)(wbf + (mat1 + 1) * 16384);
    #pragma unroll
    for (int it = 0; it < 8; ++it) {
        long off = (long)it * 4096 + tid * 16;
        gl_lds16(W1g + off, (char*)w1s + it * 4096 + w * 1024);
        if (mode < 2) gl_lds16(W2g + off, (char*)w2s + it * 4096 + w * 1024);
    }

    // A-fragments from zn (global, dense bf16)
    bf16x8 av[4];
    long mrow = m0 + w * 16 + r;
    #pragma unroll
    for (int kb = 0; kb < 4; ++kb)
        av[kb] = *(const bf16x8*)(zn + mrow * CCH + kb * 32 + kq * 8);

    f32x4 mkv = {1.f, 1.f, 1.f, 1.f};
    if (mode < 2) mkv = *(const f32x4*)(mask + m0 + w * 16 + kq * 4);

    __syncthreads();

    if (mode < 2) {
        // mfma(zn, W): j-regs -> 4 consecutive m; col r -> out channel
        u16* dst = mode ? bT : aT;
        const float* B1 = bias2 + mat1 * CCH;
        const float* B2 = bias2 + (mat1 + 1) * CCH;
        int i7 = (int)((blockIdx.x >> 3) & 7);

        f32x4 acc1[8], acc2[8];
        #pragma unroll
        for (int nt = 0; nt < 8; ++nt) { acc1[nt] = {0,0,0,0}; acc2[nt] = {0,0,0,0}; }
        #pragma unroll
        for (int nt = 0; nt < 8; ++nt) {
            int ol = nt * 16 + r;
            int key = ol & 7;
            const char* row1 = (const char*)w1s + ol * 256;
            const char* row2 = (const char*)w2s + ol * 256;
            #pragma unroll
            for (int kb = 0; kb < 4; ++kb) {
                int ph = ((kb * 4 + kq) ^ key) << 4;
                bf16x8 b1 = *(const bf16x8*)(row1 + ph);
                bf16x8 b2 = *(const bf16x8*)(row2 + ph);
                acc1[nt] = __builtin_amdgcn_mfma_f32_16x16x32_bf16(av[kb], b1, acc1[nt], 0, 0, 0);
                acc2[nt] = __builtin_amdgcn_mfma_f32_16x16x32_bf16(av[kb], b2, acc2[nt], 0, 0, 0);
            }
        }
        __syncthreads();            // all LDS weight reads drained; reuse w1s
        char* tb = (char*)w1s;      // [128 ch][144B pitch], 18432B
        int moff2 = (w * 16 + kq * 4) * 2;
        #pragma unroll
        for (int nt = 0; nt < 8; ++nt) {
            int cc = nt * 16 + r;
            float b1v = B1[cc], b2v = B2[cc];
            float v0 = mkv[0] * sigm(acc1[nt][0] + b1v) * (acc2[nt][0] + b2v);
            float v1 = mkv[1] * sigm(acc1[nt][1] + b1v) * (acc2[nt][1] + b2v);
            float v2 = mkv[2] * sigm(acc1[nt][2] + b1v) * (acc2[nt][2] + b2v);
            float v3 = mkv[3] * sigm(acc1[nt][3] + b1v) * (acc2[nt][3] + b2v);
            u32x2 pv; pv.x = pack2(v0, v1); pv.y = pack2(v2, v3);
            *(u32x2*)(tb + cc * 144 + moff2) = pv;
        }
        __syncthreads();
        // 4 rounds: 8 lanes per channel -> one full 128B line per channel
        int q = tid & 7;
        long gbase = m0 * 2 + ((long)(q ^ i7) << 4);
        #pragma unroll
        for (int rd = 0; rd < 4; ++rd) {
            int cc = rd * 32 + (tid >> 3);
            u32x4 vv = *(const u32x4*)(tb + cc * 144 + q * 16);
            *(u32x4*)((char*)dst + ((long)cc << 19) + gbase) = vv;
        }
    } else {
        // gate: mfma(W, zn): j-regs -> 4 consecutive c; col r -> m-row
        f32x4 acc[8];
        #pragma unroll
        for (int nt = 0; nt < 8; ++nt) acc[nt] = {0,0,0,0};
        #pragma unroll
        for (int nt = 0; nt < 8; ++nt) {
            int ol = nt * 16 + r;
            int key = ol & 7;
            const char* row1 = (const char*)w1s + ol * 256;
            #pragma unroll
            for (int kb = 0; kb < 4; ++kb) {
                bf16x8 b1 = *(const bf16x8*)(row1 + (((kb * 4 + kq) ^ key) << 4));
                acc[nt] = __builtin_amdgcn_mfma_f32_16x16x32_bf16(b1, av[kb], acc[nt], 0, 0, 0);
            }
        }
        long m = m0 + w * 16 + r;
        #pragma unroll
        for (int nt = 0; nt < 8; ++nt) {
            int c0 = nt * 16 + kq * 4;
            f32x4 bg = *(const f32x4*)(bias2 + 4 * CCH + c0);
            u32x2 pv;
            pv.x = pack2(sigm(acc[nt][0] + bg[0]), sigm(acc[nt][1] + bg[1]));
            pv.y = pack2(sigm(acc[nt][2] + bg[2]), sigm(acc[nt][3] + bg[3]));
            *(u32x2*)(gateB + m * 256 + c0) = pv;
        }
    }
}

// ---------------- k_tri: per-channel triangle GEMM, BK=64 ------------------
// Epilogue: accs -> LDS tile -> full-line row-major stores.
__global__ __launch_bounds__(256, 4) void k_tri(const u16* __restrict__ aT,
                                                const u16* __restrict__ bT,
                                                u16* __restrict__ xT) {
    __shared__ __align__(16) char shm[34816];  // At 16KB | Bt 16KB ; epilogue tile 34KB
    u16* At = (u16*)shm;
    u16* Bt = (u16*)(shm + 16384);
    int tid = threadIdx.x;
    int w = tid >> 6, lane = tid & 63;
    int r = lane & 15, kq = lane >> 4;

    int L = blockIdx.x;
    int xcd = L & 7, idx = L >> 3;
    int c    = xcd + 8 * (idx >> 4);
    int tile = idx & 15;
    int ti = tile >> 2, tj = tile & 3;

    const char* abase = (const char*)(aT + (long)c * MM) + (long)(ti * 128) * 1024;
    const char* bbase = (const char*)(bT + (long)c * MM) + (long)(tj * 128) * 1024;
    int wm = w >> 1, wn = w & 1;

    f32x4 acc[4][4];
    #pragma unroll
    for (int a = 0; a < 4; ++a)
        #pragma unroll
        for (int bq = 0; bq < 4; ++bq) acc[a][bq] = {0.f,0.f,0.f,0.f};

    for (int ks = 0; ks < 8; ++ks) {
        const char* asrc = abase + ks * 128;
        const char* bsrc = bbase + ks * 128;
        #pragma unroll
        for (int it = 0; it < 4; ++it) {
            int u = it * 256 + tid;
            long goff = (long)(u >> 3) * 1024 + (u & 7) * 16;
            gl_lds16(asrc + goff, (char*)At + it * 4096 + w * 1024);
            gl_lds16(bsrc + goff, (char*)Bt + it * 4096 + w * 1024);
        }
        __syncthreads();

        #pragma unroll
        for (int kh = 0; kh < 2; ++kh) {
            bf16x8 af[4];
            #pragma unroll
            for (int mt = 0; mt < 4; ++mt) {
                int rowa = wm * 64 + mt * 16 + r;
                af[mt] = *(const bf16x8*)((const char*)At + rowa * 128 +
                                          (((kh * 4 + kq) ^ (r & 7)) << 4));
            }
            #pragma unroll
            for (int nt = 0; nt < 4; ++nt) {
                int rowb = wn * 64 + nt * 16 + r;
                bf16x8 bf = *(const bf16x8*)((const char*)Bt + rowb * 128 +
                                             (((kh * 4 + kq) ^ (r & 7)) << 4));
                #pragma unroll
                for (int mt = 0; mt < 4; ++mt)
                    acc[mt][nt] = __builtin_amdgcn_mfma_f32_16x16x32_bf16(bf, af[mt], acc[mt][nt], 0, 0, 0);
            }
        }
        __syncthreads();   // also fences LDS before epilogue reuse (last iter)
    }

    // accs -> LDS tile [128 i][272B pitch] (col r = i-row, j-regs = 4 consecutive j)
    char* tb = shm;
    #pragma unroll
    for (int mt = 0; mt < 4; ++mt) {
        int il = wm * 64 + mt * 16 + r;
        #pragma unroll
        for (int nt = 0; nt < 4; ++nt) {
            int jl = wn * 64 + nt * 16 + kq * 4;
            u32x2 pv;
            pv.x = pack2(acc[mt][nt][0], acc[mt][nt][1]);
            pv.y = pack2(acc[mt][nt][2], acc[mt][nt][3]);
            *(u32x2*)(tb + il * 272 + jl * 2) = pv;
        }
    }
    __syncthreads();
    // store: 8 rounds x (4 rows x 256B contiguous per inst)
    u16* xrow = xT + (long)c * MM + (long)(ti * 128) * NN + tj * 128;
    int joff = tid & 15;
    #pragma unroll
    for (int rd = 0; rd < 8; ++rd) {
        int il = rd * 16 + (tid >> 4);
        u32x4 vv = *(const u32x4*)(tb + il * 272 + joff * 16);
        *(u32x4*)(xrow + (long)il * NN + joff * 8) = vv;
    }
}

// ---------------- k_out: LN(x) @ w_z''^T + bias2_z, * gate -----------------
// swapped mfma: j-regs -> 4 consecutive c -> f32x4 stores
__global__ __launch_bounds__(256, 4) void k_out(const u16* __restrict__ xT,
                                                const u16* __restrict__ wbf,
                                                const float* __restrict__ bias2,
                                                const u16* gateB,
                                                float* __restrict__ outp) {
    __shared__ __align__(16) u16 xl[64 * 128];  // 16KB
    int tid = threadIdx.x, w = tid >> 6, lane = tid & 63;
    int r = lane & 15, kq = lane >> 4;
    long m0 = (long)blockIdx.x * 64;

    // transpose stage: xT[c][m] -> xl[m][c], 4 channels packed per u16x4
    {
        int cg = tid & 31, ms = tid >> 5;
        int c0 = cg * 4;
        const u16* base = xT + m0 + (long)ms * 8;
        bf16x8 v0 = *(const bf16x8*)(base + (long)(c0 + 0) * MM);
        bf16x8 v1 = *(const bf16x8*)(base + (long)(c0 + 1) * MM);
        bf16x8 v2 = *(const bf16x8*)(base + (long)(c0 + 2) * MM);
        bf16x8 v3 = *(const bf16x8*)(base + (long)(c0 + 3) * MM);
        #pragma unroll
        for (int e = 0; e < 8; ++e) {
            int m = ms * 8 + e;
            u16x4 t;
            t.x = (u16)v0[e]; t.y = (u16)v1[e]; t.z = (u16)v2[e]; t.w = (u16)v3[e];
            *(u16x4*)((char*)xl + m * 256 + ((c0 * 2) ^ ((m & 15) << 4))) = t;
        }
    }
    __syncthreads();

    // A-frags as u32 pairs + LN stats via mask/shift decode
    int mlr = w * 16 + r;
    int swm = (mlr & 15) << 4;
    u32x4 avu[4];
    float s = 0.f, s2 = 0.f;
    #pragma unroll
    for (int kb = 0; kb < 4; ++kb) {
        avu[kb] = *(const u32x4*)((const char*)xl + mlr * 256 + ((kb * 64 + kq * 16) ^ swm));
        #pragma unroll
        for (int p = 0; p < 4; ++p) {
            unsigned u = avu[kb][p];
            float flo = __builtin_bit_cast(float, u << 16);
            float fhi = __builtin_bit_cast(float, u & 0xFFFF0000u);
            s += flo + fhi;
            s2 = fmaf(flo, flo, s2);
            s2 = fmaf(fhi, fhi, s2);
        }
    }
    s  += __shfl_xor(s, 16);  s  += __shfl_xor(s, 32);
    s2 += __shfl_xor(s2, 16); s2 += __shfl_xor(s2, 32);
    float mu = s * (1.0f / CCH);
    float var = fmaxf(s2 * (1.0f / CCH) - mu * mu, 0.f);
    float rs = rsqrtf(var + 1e-5f);
    float nmu = -mu * rs;
    bf16x8 av[4];
    #pragma unroll
    for (int kb = 0; kb < 4; ++kb) {
        u32x4 o;
        #pragma unroll
        for (int p = 0; p < 4; ++p) {
            unsigned u = avu[kb][p];
            float flo = __builtin_bit_cast(float, u << 16);
            float fhi = __builtin_bit_cast(float, u & 0xFFFF0000u);
            o[p] = pack2(fmaf(flo, rs, nmu), fmaf(fhi, rs, nmu));
        }
        av[kb] = __builtin_bit_cast(bf16x8, o);
    }

    // gate preload (gateB aliases outp rows of THIS block only)
    long m = m0 + w * 16 + r;
    u16x4 gvu[8];
    #pragma unroll
    for (int nt = 0; nt < 8; ++nt)
        gvu[nt] = *(const u16x4*)(gateB + m * 256 + nt * 16 + kq * 4);

    // swapped MFMA vs w_z'' (global reads, chunk-swizzled layout)
    const char* Wz = (const char*)(wbf + 5 * 16384);
    f32x4 acc[8];
    #pragma unroll
    for (int nt = 0; nt < 8; ++nt) acc[nt] = {0,0,0,0};
    #pragma unroll
    for (int nt = 0; nt < 8; ++nt) {
        int ol = nt * 16 + r;
        int key = ol & 7;
        const char* row = Wz + ol * 256;
        #pragma unroll
        for (int kb = 0; kb < 4; ++kb) {
            bf16x8 bw = *(const bf16x8*)(row + (((kb * 4 + kq) ^ key) << 4));
            acc[nt] = __builtin_amdgcn_mfma_f32_16x16x32_bf16(bw, av[kb], acc[nt], 0, 0, 0);
        }
    }

    __syncthreads();   // ALL gate loads done before any aliasing store

    const float* b2z = bias2 + 5 * CCH;
    #pragma unroll
    for (int nt = 0; nt < 8; ++nt) {
        int c0 = nt * 16 + kq * 4;
        f32x4 bb = *(const f32x4*)(b2z + c0);
        f32x4 o;
        #pragma unroll
        for (int j = 0; j < 4; ++j)
            o[j] = (acc[nt][j] + bb[j]) * bf2f(gvu[nt][j]);
        *(f32x4*)(outp + m * CCH + c0) = o;
    }
}

extern "C" void kernel_launch(void* const* d_in, const int* in_sizes, int n_in,
                              void* d_out, int out_size, void* d_ws, size_t ws_size,
                              hipStream_t stream) {
    const float* z       = (const float*)d_in[0];
    const float* mask    = (const float*)d_in[1];
    const float* ln_in_g = (const float*)d_in[2];
    const float* ln_in_b = (const float*)d_in[3];
    const float* w_ag    = (const float*)d_in[4];
    const float* b_ag    = (const float*)d_in[5];
    const float* w_ap    = (const float*)d_in[6];
    const float* b_ap    = (const float*)d_in[7];
    const float* w_bg    = (const float*)d_in[8];
    const float* b_bg    = (const float*)d_in[9];
    const float* w_bp    = (const float*)d_in[10];
    const float* b_bp    = (const float*)d_in[11];
    const float* w_g     = (const float*)d_in[12];
    const float* b_g     = (const float*)d_in[13];
    const float* w_z     = (const float*)d_in[14];
    const float* b_z     = (const float*)d_in[15];
    const float* ln_o_g  = (const float*)d_in[16];
    const float* ln_o_b  = (const float*)d_in[17];
    float* out = (float*)d_out;
    u16* gateB = (u16*)d_out;   // gate bf16 in first 256B of each 512B d_out row

    char* ws = (char*)d_ws;
    const size_t SL = (size_t)MM * CCH * 2;  // 64MB per slot
    u16* xT   = (u16*)ws;
    u16* aT   = (u16*)(ws + SL);
    u16* bT   = (u16*)(ws + 2 * SL);
    u16* zn   = (u16*)(ws + 3 * SL);
    u16* wbf  = (u16*)(ws + 4 * SL);                       // 192KB swizzled bf16 weights
    float* b2 = (float*)(ws + 4 * SL + 6 * 16384 * 2);     // 3KB folded biases

    k_prep<<<6, 256, 0, stream>>>(w_ag, w_ap, w_bg, w_bp, w_g, w_z,
                                  b_ag, b_ap, b_bg, b_bp, b_g, b_z,
                                  ln_in_g, ln_in_b, ln_o_g, ln_o_b, wbf, b2);
    k_ln<<<MM / 4, 256, 0, stream>>>(z, zn);
    k_proj<<<dim3(MM / 64, 3), 256, 0, stream>>>(zn, mask, wbf, b2, aT, bT, gateB);
    k_tri<<<2048, 256, 0, stream>>>(aT, bT, xT);
    k_out<<<MM / 64, 256, 0, stream>>>(xT, wbf, b2, gateB, out);
}

// Round 11
// 316.810 us; speedup vs baseline: 1.6973x; 1.0493x over previous
//
#include <hip/hip_runtime.h>

#define NN 512
#define CCH 128
#define MM (NN*NN)   // 262144

using f32x4  = __attribute__((ext_vector_type(4))) float;
using f32x2  = __attribute__((ext_vector_type(2))) float;
using bf16x8 = __attribute__((ext_vector_type(8))) short;
using u16x4  = __attribute__((ext_vector_type(4))) unsigned short;
using u32x2  = __attribute__((ext_vector_type(2))) unsigned int;
using u32x4  = __attribute__((ext_vector_type(4))) unsigned int;
typedef unsigned short u16;

__device__ __forceinline__ u16 f2bf(float f) {
    unsigned u = __builtin_bit_cast(unsigned, f);
    u += 0x7FFF + ((u >> 16) & 1);
    return (u16)(u >> 16);
}
__device__ __forceinline__ float bf2f(u16 h) {
    unsigned u = ((unsigned)h) << 16;
    return __builtin_bit_cast(float, u);
}
__device__ __forceinline__ unsigned pack2(float lo, float hi) {
    return (unsigned)f2bf(lo) | ((unsigned)f2bf(hi) << 16);
}
__device__ __forceinline__ float sigm(float x) { return 1.0f / (1.0f + __expf(-x)); }

__device__ __forceinline__ void gl_lds16(const void* g, void* l) {
    __builtin_amdgcn_global_load_lds(
        (const __attribute__((address_space(1))) void*)g,
        (__attribute__((address_space(3))) void*)l, 16, 0, 0);
}

// ---------------- k_prep: fold LN gamma/beta into bf16 weights + biases ----
// Weight rows stored CHUNK-SWIZZLED: logical 16B chunk q of row o lives at
// physical chunk (q ^ (o&7)).
__global__ __launch_bounds__(256) void k_prep(
    const float* __restrict__ w0, const float* __restrict__ w1,
    const float* __restrict__ w2, const float* __restrict__ w3,
    const float* __restrict__ w4, const float* __restrict__ w5,
    const float* __restrict__ b0, const float* __restrict__ b1,
    const float* __restrict__ b2, const float* __restrict__ b3,
    const float* __restrict__ b4, const float* __restrict__ b5,
    const float* __restrict__ gin, const float* __restrict__ bin,
    const float* __restrict__ gout, const float* __restrict__ bout,
    u16* __restrict__ wbf, float* __restrict__ bias2) {
    int mat = blockIdx.x;
    const float* W = mat==0?w0:mat==1?w1:mat==2?w2:mat==3?w3:mat==4?w4:w5;
    const float* B = mat==0?b0:mat==1?b1:mat==2?b2:mat==3?b3:mat==4?b4:b5;
    const float* G = (mat==5)? gout : gin;
    const float* Bt= (mat==5)? bout : bin;
    __shared__ float gs[CCH], bs[CCH];
    int tid = threadIdx.x;
    if (tid < CCH) { gs[tid] = G[tid]; bs[tid] = Bt[tid]; }
    __syncthreads();
    int o = tid >> 1, c0 = (tid & 1) * 64;
    const float* src = W + o * CCH + c0;
    char* dstrow = (char*)(wbf + mat * 16384) + o * 256;
    int key = o & 7;
    float dot = 0.f;
    #pragma unroll
    for (int q = 0; q < 16; ++q) {
        f32x4 v = *(const f32x4*)(src + q * 4);
        int c = c0 + q * 4;
        dot += bs[c]*v.x + bs[c+1]*v.y + bs[c+2]*v.z + bs[c+3]*v.w;
        u16x4 p;
        p.x = f2bf(v.x * gs[c]);     p.y = f2bf(v.y * gs[c+1]);
        p.z = f2bf(v.z * gs[c+2]);   p.w = f2bf(v.w * gs[c+3]);
        int chunk = (c0 >> 3) + (q >> 1);
        *(u16x4*)(dstrow + (((chunk ^ key)) << 4) + ((q & 1) << 3)) = p;
    }
    dot += __shfl_xor(dot, 1);
    if ((tid & 1) == 0) bias2[mat * CCH + o] = B[o] + dot;
}

// ---------------- k_fused: LN(z) + all 5 projections, one 64-row block -----
// LDS: zn tile 16KB + weight buffer 64KB (2 matrices) = 80KB -> 2 blocks/CU.
// Phases: [stage pairA issued at entry] LN -> barrier -> MFMA pairA -> aT;
// restage pairB -> MFMA -> bT; restage gate -> MFMA(swapped) -> gateB.
// av fragments live in registers across all phases (zn read from LDS once).
__global__ __launch_bounds__(256) void k_fused(
    const float* __restrict__ z, const float* __restrict__ mask,
    const u16* __restrict__ wbf, const float* __restrict__ bias2,
    u16* __restrict__ aT, u16* __restrict__ bT, u16* gateB) {
    __shared__ __align__(16) u16 znt[8192];    // 16KB: [64 rows][256B] swizzled
    __shared__ __align__(16) u16 wls[32768];   // 64KB: two 32KB weight matrices
    int tid = threadIdx.x, w = tid >> 6, lane = tid & 63;
    int r = lane & 15, kq = lane >> 4;
    long m0 = (long)blockIdx.x * 64;

    // stage pair-A weights (mats 0,1 contiguous 64KB) — hides under LN
    {
        const char* Wg = (const char*)wbf;
        #pragma unroll
        for (int it = 0; it < 16; ++it)
            gl_lds16(Wg + (long)it * 4096 + tid * 16, (char*)wls + it * 4096 + w * 1024);
    }

    // LN phase: 4 threads per row
    {
        int row = tid >> 2, p = tid & 3, c0 = p * 32;
        const float* zr = z + (m0 + row) * CCH + c0;
        f32x4 va[8];
        float s = 0.f, s2 = 0.f;
        #pragma unroll
        for (int q = 0; q < 8; ++q) {
            va[q] = *(const f32x4*)(zr + q * 4);
            s  += va[q].x + va[q].y + va[q].z + va[q].w;
            s2 += va[q].x*va[q].x + va[q].y*va[q].y + va[q].z*va[q].z + va[q].w*va[q].w;
        }
        s += __shfl_xor(s, 1);  s += __shfl_xor(s, 2);
        s2 += __shfl_xor(s2, 1); s2 += __shfl_xor(s2, 2);
        float mu = s * (1.0f / CCH);
        float var = fmaxf(s2 * (1.0f / CCH) - mu * mu, 0.f);
        float rs = rsqrtf(var + 1e-5f);
        int sw = (row & 15) << 4;
        #pragma unroll
        for (int q2 = 0; q2 < 4; ++q2) {
            f32x4 v0 = va[q2*2], v1 = va[q2*2+1];
            u32x2 pk;
            pk.x = pack2((v0.x-mu)*rs, (v0.y-mu)*rs);
            pk.y = pack2((v0.z-mu)*rs, (v0.w-mu)*rs);
            u32x2 pk2;
            pk2.x = pack2((v1.x-mu)*rs, (v1.y-mu)*rs);
            pk2.y = pack2((v1.z-mu)*rs, (v1.w-mu)*rs);
            char* p8 = (char*)znt + row * 256 + ((c0 * 2 + q2 * 16) ^ sw);
            *(u32x2*)p8 = pk;
            *(u32x2*)(p8 + 8) = pk2;
        }
    }
    __syncthreads();   // znt ready AND pair-A staging drained

    // A-fragments from LDS — live across all phases
    bf16x8 av[4];
    {
        int row = w * 16 + r, sw = (row & 15) << 4;
        #pragma unroll
        for (int kb = 0; kb < 4; ++kb)
            av[kb] = *(const bf16x8*)((const char*)znt + row * 256 + ((kb * 64 + kq * 16) ^ sw));
    }
    f32x4 mkv = *(const f32x4*)(mask + m0 + w * 16 + kq * 4);

    int i7 = (int)((blockIdx.x >> 3) & 7);
    int qch = w * 2 + (kq >> 1);
    long boff = m0 * 2 + (long)((qch ^ i7) << 4) + ((kq & 1) << 3);

    // pair phases: ph 0 -> aT (mats 0,1); ph 1 -> bT (mats 2,3)
    #pragma unroll 1
    for (int ph = 0; ph < 2; ++ph) {
        if (ph == 1) {
            __syncthreads();   // phase-0 wls reads done
            const char* Wg = (const char*)wbf + 65536;
            #pragma unroll
            for (int it = 0; it < 16; ++it)
                gl_lds16(Wg + (long)it * 4096 + tid * 16, (char*)wls + it * 4096 + w * 1024);
            __syncthreads();
        }
        const float* B1 = bias2 + (ph * 2) * CCH;
        const float* B2 = bias2 + (ph * 2 + 1) * CCH;
        f32x4 acc1[8], acc2[8];
        #pragma unroll
        for (int nt = 0; nt < 8; ++nt) { acc1[nt] = {0,0,0,0}; acc2[nt] = {0,0,0,0}; }
        #pragma unroll
        for (int nt = 0; nt < 8; ++nt) {
            int ol = nt * 16 + r;
            int key = ol & 7;
            const char* row1 = (const char*)wls + ol * 256;
            const char* row2 = (const char*)wls + 32768 + ol * 256;
            #pragma unroll
            for (int kb = 0; kb < 4; ++kb) {
                int ph16 = ((kb * 4 + kq) ^ key) << 4;
                bf16x8 b1 = *(const bf16x8*)(row1 + ph16);
                bf16x8 b2 = *(const bf16x8*)(row2 + ph16);
                acc1[nt] = __builtin_amdgcn_mfma_f32_16x16x32_bf16(av[kb], b1, acc1[nt], 0, 0, 0);
                acc2[nt] = __builtin_amdgcn_mfma_f32_16x16x32_bf16(av[kb], b2, acc2[nt], 0, 0, 0);
            }
        }
        u16* dst = ph ? bT : aT;
        #pragma unroll
        for (int nt = 0; nt < 8; ++nt) {
            int cc = nt * 16 + r;
            float b1v = B1[cc], b2v = B2[cc];
            float v0 = mkv[0] * sigm(acc1[nt][0] + b1v) * (acc2[nt][0] + b2v);
            float v1 = mkv[1] * sigm(acc1[nt][1] + b1v) * (acc2[nt][1] + b2v);
            float v2 = mkv[2] * sigm(acc1[nt][2] + b1v) * (acc2[nt][2] + b2v);
            float v3 = mkv[3] * sigm(acc1[nt][3] + b1v) * (acc2[nt][3] + b2v);
            u32x2 pv; pv.x = pack2(v0, v1); pv.y = pack2(v2, v3);
            *(u32x2*)((char*)dst + ((long)cc << 19) + boff) = pv;
        }
    }

    // gate phase: mfma(W, zn) swapped -> j-regs = 4 consecutive c
    __syncthreads();   // pair-B wls reads done
    {
        const char* Wg = (const char*)wbf + 131072;   // mat 4 (32KB)
        #pragma unroll
        for (int it = 0; it < 8; ++it)
            gl_lds16(Wg + (long)it * 4096 + tid * 16, (char*)wls + it * 4096 + w * 1024);
    }
    __syncthreads();
    {
        f32x4 acc[8];
        #pragma unroll
        for (int nt = 0; nt < 8; ++nt) acc[nt] = {0,0,0,0};
        #pragma unroll
        for (int nt = 0; nt < 8; ++nt) {
            int ol = nt * 16 + r;
            int key = ol & 7;
            const char* row1 = (const char*)wls + ol * 256;
            #pragma unroll
            for (int kb = 0; kb < 4; ++kb) {
                bf16x8 b1 = *(const bf16x8*)(row1 + (((kb * 4 + kq) ^ key) << 4));
                acc[nt] = __builtin_amdgcn_mfma_f32_16x16x32_bf16(b1, av[kb], acc[nt], 0, 0, 0);
            }
        }
        long m = m0 + w * 16 + r;
        #pragma unroll
        for (int nt = 0; nt < 8; ++nt) {
            int c0 = nt * 16 + kq * 4;
            f32x4 bg = *(const f32x4*)(bias2 + 4 * CCH + c0);
            u32x2 pv;
            pv.x = pack2(sigm(acc[nt][0] + bg[0]), sigm(acc[nt][1] + bg[1]));
            pv.y = pack2(sigm(acc[nt][2] + bg[2]), sigm(acc[nt][3] + bg[3]));
            *(u32x2*)(gateB + m * 256 + c0) = pv;
        }
    }
}

// ---------------- k_tri: per-channel triangle GEMM, BK=64 ------------------
// Epilogue: accs -> LDS tile -> full-line row-major stores.
__global__ __launch_bounds__(256, 4) void k_tri(const u16* __restrict__ aT,
                                                const u16* __restrict__ bT,
                                                u16* __restrict__ xT) {
    __shared__ __align__(16) char shm[34816];  // At 16KB | Bt 16KB ; epilogue tile 34KB
    u16* At = (u16*)shm;
    u16* Bt = (u16*)(shm + 16384);
    int tid = threadIdx.x;
    int w = tid >> 6, lane = tid & 63;
    int r = lane & 15, kq = lane >> 4;

    int L = blockIdx.x;
    int xcd = L & 7, idx = L >> 3;
    int c    = xcd + 8 * (idx >> 4);
    int tile = idx & 15;
    int ti = tile >> 2, tj = tile & 3;

    const char* abase = (const char*)(aT + (long)c * MM) + (long)(ti * 128) * 1024;
    const char* bbase = (const char*)(bT + (long)c * MM) + (long)(tj * 128) * 1024;
    int wm = w >> 1, wn = w & 1;

    f32x4 acc[4][4];
    #pragma unroll
    for (int a = 0; a < 4; ++a)
        #pragma unroll
        for (int bq = 0; bq < 4; ++bq) acc[a][bq] = {0.f,0.f,0.f,0.f};

    for (int ks = 0; ks < 8; ++ks) {
        const char* asrc = abase + ks * 128;
        const char* bsrc = bbase + ks * 128;
        #pragma unroll
        for (int it = 0; it < 4; ++it) {
            int u = it * 256 + tid;
            long goff = (long)(u >> 3) * 1024 + (u & 7) * 16;
            gl_lds16(asrc + goff, (char*)At + it * 4096 + w * 1024);
            gl_lds16(bsrc + goff, (char*)Bt + it * 4096 + w * 1024);
        }
        __syncthreads();

        #pragma unroll
        for (int kh = 0; kh < 2; ++kh) {
            bf16x8 af[4];
            #pragma unroll
            for (int mt = 0; mt < 4; ++mt) {
                int rowa = wm * 64 + mt * 16 + r;
                af[mt] = *(const bf16x8*)((const char*)At + rowa * 128 +
                                          (((kh * 4 + kq) ^ (r & 7)) << 4));
            }
            #pragma unroll
            for (int nt = 0; nt < 4; ++nt) {
                int rowb = wn * 64 + nt * 16 + r;
                bf16x8 bf = *(const bf16x8*)((const char*)Bt + rowb * 128 +
                                             (((kh * 4 + kq) ^ (r & 7)) << 4));
                #pragma unroll
                for (int mt = 0; mt < 4; ++mt)
                    acc[mt][nt] = __builtin_amdgcn_mfma_f32_16x16x32_bf16(bf, af[mt], acc[mt][nt], 0, 0, 0);
            }
        }
        __syncthreads();   // also fences LDS before epilogue reuse (last iter)
    }

    // accs -> LDS tile [128 i][272B pitch] (col r = i-row, j-regs = 4 consecutive j)
    char* tb = shm;
    #pragma unroll
    for (int mt = 0; mt < 4; ++mt) {
        int il = wm * 64 + mt * 16 + r;
        #pragma unroll
        for (int nt = 0; nt < 4; ++nt) {
            int jl = wn * 64 + nt * 16 + kq * 4;
            u32x2 pv;
            pv.x = pack2(acc[mt][nt][0], acc[mt][nt][1]);
            pv.y = pack2(acc[mt][nt][2], acc[mt][nt][3]);
            *(u32x2*)(tb + il * 272 + jl * 2) = pv;
        }
    }
    __syncthreads();
    // store: 8 rounds x (4 rows x 256B contiguous per inst)
    u16* xrow = xT + (long)c * MM + (long)(ti * 128) * NN + tj * 128;
    int joff = tid & 15;
    #pragma unroll
    for (int rd = 0; rd < 8; ++rd) {
        int il = rd * 16 + (tid >> 4);
        u32x4 vv = *(const u32x4*)(tb + il * 272 + joff * 16);
        *(u32x4*)(xrow + (long)il * NN + joff * 8) = vv;
    }
}

// ---------------- k_out: LN(x) @ w_z''^T + bias2_z, * gate -----------------
// swapped mfma: j-regs -> 4 consecutive c -> f32x4 stores
__global__ __launch_bounds__(256, 4) void k_out(const u16* __restrict__ xT,
                                                const u16* __restrict__ wbf,
                                                const float* __restrict__ bias2,
                                                const u16* gateB,
                                                float* __restrict__ outp) {
    __shared__ __align__(16) u16 xl[64 * 128];  // 16KB
    int tid = threadIdx.x, w = tid >> 6, lane = tid & 63;
    int r = lane & 15, kq = lane >> 4;
    long m0 = (long)blockIdx.x * 64;

    // transpose stage: xT[c][m] -> xl[m][c], 4 channels packed per u16x4
    {
        int cg = tid & 31, ms = tid >> 5;
        int c0 = cg * 4;
        const u16* base = xT + m0 + (long)ms * 8;
        bf16x8 v0 = *(const bf16x8*)(base + (long)(c0 + 0) * MM);
        bf16x8 v1 = *(const bf16x8*)(base + (long)(c0 + 1) * MM);
        bf16x8 v2 = *(const bf16x8*)(base + (long)(c0 + 2) * MM);
        bf16x8 v3 = *(const bf16x8*)(base + (long)(c0 + 3) * MM);
        #pragma unroll
        for (int e = 0; e < 8; ++e) {
            int m = ms * 8 + e;
            u16x4 t;
            t.x = (u16)v0[e]; t.y = (u16)v1[e]; t.z = (u16)v2[e]; t.w = (u16)v3[e];
            *(u16x4*)((char*)xl + m * 256 + ((c0 * 2) ^ ((m & 15) << 4))) = t;
        }
    }
    __syncthreads();

    // A-frags as u32 pairs + LN stats via mask/shift decode
    int mlr = w * 16 + r;
    int swm = (mlr & 15) << 4;
    u32x4 avu[4];
    float s = 0.f, s2 = 0.f;
    #pragma unroll
    for (int kb = 0; kb < 4; ++kb) {
        avu[kb] = *(const u32x4*)((const char*)xl + mlr * 256 + ((kb * 64 + kq * 16) ^ swm));
        #pragma unroll
        for (int p = 0; p < 4; ++p) {
            unsigned u = avu[kb][p];
            float flo = __builtin_bit_cast(float, u << 16);
            float fhi = __builtin_bit_cast(float, u & 0xFFFF0000u);
            s += flo + fhi;
            s2 = fmaf(flo, flo, s2);
            s2 = fmaf(fhi, fhi, s2);
        }
    }
    s  += __shfl_xor(s, 16);  s  += __shfl_xor(s, 32);
    s2 += __shfl_xor(s2, 16); s2 += __shfl_xor(s2, 32);
    float mu = s * (1.0f / CCH);
    float var = fmaxf(s2 * (1.0f / CCH) - mu * mu, 0.f);
    float rs = rsqrtf(var + 1e-5f);
    float nmu = -mu * rs;
    bf16x8 av[4];
    #pragma unroll
    for (int kb = 0; kb < 4; ++kb) {
        u32x4 o;
        #pragma unroll
        for (int p = 0; p < 4; ++p) {
            unsigned u = avu[kb][p];
            float flo = __builtin_bit_cast(float, u << 16);
            float fhi = __builtin_bit_cast(float, u & 0xFFFF0000u);
            o[p] = pack2(fmaf(flo, rs, nmu), fmaf(fhi, rs, nmu));
        }
        av[kb] = __builtin_bit_cast(bf16x8, o);
    }

    // gate preload (gateB aliases outp rows of THIS block only)
    long m = m0 + w * 16 + r;
    u16x4 gvu[8];
    #pragma unroll
    for (int nt = 0; nt < 8; ++nt)
        gvu[nt] = *(const u16x4*)(gateB + m * 256 + nt * 16 + kq * 4);

    // swapped MFMA vs w_z'' (global reads, chunk-swizzled layout)
    const char* Wz = (const char*)(wbf + 5 * 16384);
    f32x4 acc[8];
    #pragma unroll
    for (int nt = 0; nt < 8; ++nt) acc[nt] = {0,0,0,0};
    #pragma unroll
    for (int nt = 0; nt < 8; ++nt) {
        int ol = nt * 16 + r;
        int key = ol & 7;
        const char* row = Wz + ol * 256;
        #pragma unroll
        for (int kb = 0; kb < 4; ++kb) {
            bf16x8 bw = *(const bf16x8*)(row + (((kb * 4 + kq) ^ key) << 4));
            acc[nt] = __builtin_amdgcn_mfma_f32_16x16x32_bf16(bw, av[kb], acc[nt], 0, 0, 0);
        }
    }

    __syncthreads();   // ALL gate loads done before any aliasing store

    const float* b2z = bias2 + 5 * CCH;
    #pragma unroll
    for (int nt = 0; nt < 8; ++nt) {
        int c0 = nt * 16 + kq * 4;
        f32x4 bb = *(const f32x4*)(b2z + c0);
        f32x4 o;
        #pragma unroll
        for (int j = 0; j < 4; ++j)
            o[j] = (acc[nt][j] + bb[j]) * bf2f(gvu[nt][j]);
        *(f32x4*)(outp + m * CCH + c0) = o;
    }
}

extern "C" void kernel_launch(void* const* d_in, const int* in_sizes, int n_in,
                              void* d_out, int out_size, void* d_ws, size_t ws_size,
                              hipStream_t stream) {
    const float* z       = (const float*)d_in[0];
    const float* mask    = (const float*)d_in[1];
    const float* ln_in_g = (const float*)d_in[2];
    const float* ln_in_b = (const float*)d_in[3];
    const float* w_ag    = (const float*)d_in[4];
    const float* b_ag    = (const float*)d_in[5];
    const float* w_ap    = (const float*)d_in[6];
    const float* b_ap    = (const float*)d_in[7];
    const float* w_bg    = (const float*)d_in[8];
    const float* b_bg    = (const float*)d_in[9];
    const float* w_bp    = (const float*)d_in[10];
    const float* b_bp    = (const float*)d_in[11];
    const float* w_g     = (const float*)d_in[12];
    const float* b_g     = (const float*)d_in[13];
    const float* w_z     = (const float*)d_in[14];
    const float* b_z     = (const float*)d_in[15];
    const float* ln_o_g  = (const float*)d_in[16];
    const float* ln_o_b  = (const float*)d_in[17];
    float* out = (float*)d_out;
    u16* gateB = (u16*)d_out;   // gate bf16 in first 256B of each 512B d_out row

    char* ws = (char*)d_ws;
    const size_t SL = (size_t)MM * CCH * 2;  // 64MB per slot
    u16* xT   = (u16*)ws;
    u16* aT   = (u16*)(ws + SL);
    u16* bT   = (u16*)(ws + 2 * SL);
    u16* wbf  = (u16*)(ws + 3 * SL);                       // 192KB swizzled bf16 weights
    float* b2 = (float*)(ws + 3 * SL + 6 * 16384 * 2);     // 3KB folded biases

    k_prep<<<6, 256, 0, stream>>>(w_ag, w_ap, w_bg, w_bp, w_g, w_z,
                                  b_ag, b_ap, b_bg, b_bp, b_g, b_z,
                                  ln_in_g, ln_in_b, ln_o_g, ln_o_b, wbf, b2);
    k_fused<<<MM / 64, 256, 0, stream>>>(z, mask, wbf, b2, aT, bT, gateB);
    k_tri<<<2048, 256, 0, stream>>>(aT, bT, xT);
    k_out<<<MM / 64, 256, 0, stream>>>(xT, wbf, b2, gateB, out);
}

// Round 12
// 311.270 us; speedup vs baseline: 1.7275x; 1.0178x over previous
//
#include <hip/hip_runtime.h>

#define NN 512
#define CCH 128
#define MM (NN*NN)   // 262144

using f32x4  = __attribute__((ext_vector_type(4))) float;
using f32x2  = __attribute__((ext_vector_type(2))) float;
using bf16x8 = __attribute__((ext_vector_type(8))) short;
using u16x4  = __attribute__((ext_vector_type(4))) unsigned short;
using u32x2  = __attribute__((ext_vector_type(2))) unsigned int;
using u32x4  = __attribute__((ext_vector_type(4))) unsigned int;
typedef unsigned short u16;

__device__ __forceinline__ u16 f2bf(float f) {
    unsigned u = __builtin_bit_cast(unsigned, f);
    u += 0x7FFF + ((u >> 16) & 1);
    return (u16)(u >> 16);
}
__device__ __forceinline__ float bf2f(u16 h) {
    unsigned u = ((unsigned)h) << 16;
    return __builtin_bit_cast(float, u);
}
__device__ __forceinline__ unsigned pack2(float lo, float hi) {
    return (unsigned)f2bf(lo) | ((unsigned)f2bf(hi) << 16);
}
__device__ __forceinline__ float sigm(float x) { return 1.0f / (1.0f + __expf(-x)); }

__device__ __forceinline__ void gl_lds16(const void* g, void* l) {
    __builtin_amdgcn_global_load_lds(
        (const __attribute__((address_space(1))) void*)g,
        (__attribute__((address_space(3))) void*)l, 16, 0, 0);
}

// ---------------- k_prep: fold LN gamma/beta into bf16 weights + biases ----
// Weight rows stored CHUNK-SWIZZLED: logical 16B chunk q of row o lives at
// physical chunk (q ^ (o&7)).
__global__ __launch_bounds__(256) void k_prep(
    const float* __restrict__ w0, const float* __restrict__ w1,
    const float* __restrict__ w2, const float* __restrict__ w3,
    const float* __restrict__ w4, const float* __restrict__ w5,
    const float* __restrict__ b0, const float* __restrict__ b1,
    const float* __restrict__ b2, const float* __restrict__ b3,
    const float* __restrict__ b4, const float* __restrict__ b5,
    const float* __restrict__ gin, const float* __restrict__ bin,
    const float* __restrict__ gout, const float* __restrict__ bout,
    u16* __restrict__ wbf, float* __restrict__ bias2) {
    int mat = blockIdx.x;
    const float* W = mat==0?w0:mat==1?w1:mat==2?w2:mat==3?w3:mat==4?w4:w5;
    const float* B = mat==0?b0:mat==1?b1:mat==2?b2:mat==3?b3:mat==4?b4:b5;
    const float* G = (mat==5)? gout : gin;
    const float* Bt= (mat==5)? bout : bin;
    __shared__ float gs[CCH], bs[CCH];
    int tid = threadIdx.x;
    if (tid < CCH) { gs[tid] = G[tid]; bs[tid] = Bt[tid]; }
    __syncthreads();
    int o = tid >> 1, c0 = (tid & 1) * 64;
    const float* src = W + o * CCH + c0;
    char* dstrow = (char*)(wbf + mat * 16384) + o * 256;
    int key = o & 7;
    float dot = 0.f;
    #pragma unroll
    for (int q = 0; q < 16; ++q) {
        f32x4 v = *(const f32x4*)(src + q * 4);
        int c = c0 + q * 4;
        dot += bs[c]*v.x + bs[c+1]*v.y + bs[c+2]*v.z + bs[c+3]*v.w;
        u16x4 p;
        p.x = f2bf(v.x * gs[c]);     p.y = f2bf(v.y * gs[c+1]);
        p.z = f2bf(v.z * gs[c+2]);   p.w = f2bf(v.w * gs[c+3]);
        int chunk = (c0 >> 3) + (q >> 1);
        *(u16x4*)(dstrow + (((chunk ^ key)) << 4) + ((q & 1) << 3)) = p;
    }
    dot += __shfl_xor(dot, 1);
    if ((tid & 1) == 0) bias2[mat * CCH + o] = B[o] + dot;
}

// ---------------- k_fused: LN(z) + all 5 projections, 128 rows/block -------
// 512 threads (8 waves). LN in REGISTERS (fragment layout, shfl row-reduce).
// LDS = 64KB weights only -> 2 blocks/CU = 4 waves/SIMD.
__global__ __launch_bounds__(512, 4) void k_fused(
    const float* __restrict__ z, const float* __restrict__ mask,
    const u16* __restrict__ wbf, const float* __restrict__ bias2,
    u16* __restrict__ aT, u16* __restrict__ bT, u16* gateB) {
    __shared__ __align__(16) u16 wls[32768];   // 64KB: two 32KB weight matrices
    int tid = threadIdx.x, w = tid >> 6, lane = tid & 63;
    int r = lane & 15, kq = lane >> 4;
    long m0 = (long)blockIdx.x * 128;

    // stage pair-A weights (mats 0,1 contiguous 64KB) — hides under LN
    {
        const char* Wg = (const char*)wbf;
        #pragma unroll
        for (int it = 0; it < 8; ++it)
            gl_lds16(Wg + (long)it * 8192 + tid * 16, (char*)wls + it * 8192 + w * 1024);
    }

    // LN in registers: lane (w,r,kq) owns row m0+w*16+r, channels kb*32+kq*8+e
    long mrow = m0 + w * 16 + r;
    bf16x8 av[4];
    {
        const float* zr = z + mrow * CCH;
        f32x4 zv[4][2];
        float s = 0.f, s2 = 0.f;
        #pragma unroll
        for (int kb = 0; kb < 4; ++kb) {
            zv[kb][0] = *(const f32x4*)(zr + kb * 32 + kq * 8);
            zv[kb][1] = *(const f32x4*)(zr + kb * 32 + kq * 8 + 4);
            #pragma unroll
            for (int h = 0; h < 2; ++h) {
                f32x4 v = zv[kb][h];
                s += v.x + v.y + v.z + v.w;
                s2 = fmaf(v.x, v.x, fmaf(v.y, v.y, fmaf(v.z, v.z, fmaf(v.w, v.w, s2))));
            }
        }
        s  += __shfl_xor(s, 16);  s  += __shfl_xor(s, 32);
        s2 += __shfl_xor(s2, 16); s2 += __shfl_xor(s2, 32);
        float mu = s * (1.0f / CCH);
        float var = fmaxf(s2 * (1.0f / CCH) - mu * mu, 0.f);
        float rs = rsqrtf(var + 1e-5f);
        #pragma unroll
        for (int kb = 0; kb < 4; ++kb) {
            f32x4 a0 = zv[kb][0], a1 = zv[kb][1];
            u32x4 o;
            o[0] = pack2((a0.x - mu) * rs, (a0.y - mu) * rs);
            o[1] = pack2((a0.z - mu) * rs, (a0.w - mu) * rs);
            o[2] = pack2((a1.x - mu) * rs, (a1.y - mu) * rs);
            o[3] = pack2((a1.z - mu) * rs, (a1.w - mu) * rs);
            av[kb] = __builtin_bit_cast(bf16x8, o);
        }
    }
    f32x4 mkv = *(const f32x4*)(mask + m0 + w * 16 + kq * 4);

    __syncthreads();   // pair-A staging drained

    int i7 = (int)((blockIdx.x >> 2) & 7);
    int q = w * 2 + (kq >> 1);                 // m_local/8 in [0,16)
    long boff = m0 * 2 + ((long)(q >> 3) << 7) + ((long)((q & 7) ^ i7) << 4)
              + ((kq & 1) << 3);

    // pair phases: ph 0 -> aT (mats 0,1); ph 1 -> bT (mats 2,3)
    #pragma unroll 1
    for (int ph = 0; ph < 2; ++ph) {
        if (ph == 1) {
            __syncthreads();   // phase-0 wls reads done
            const char* Wg = (const char*)wbf + 65536;
            #pragma unroll
            for (int it = 0; it < 8; ++it)
                gl_lds16(Wg + (long)it * 8192 + tid * 16, (char*)wls + it * 8192 + w * 1024);
            __syncthreads();
        }
        const float* B1 = bias2 + (ph * 2) * CCH;
        const float* B2 = bias2 + (ph * 2 + 1) * CCH;
        f32x4 acc1[8], acc2[8];
        #pragma unroll
        for (int nt = 0; nt < 8; ++nt) { acc1[nt] = {0,0,0,0}; acc2[nt] = {0,0,0,0}; }
        #pragma unroll
        for (int nt = 0; nt < 8; ++nt) {
            int ol = nt * 16 + r;
            int key = ol & 7;
            const char* row1 = (const char*)wls + ol * 256;
            const char* row2 = (const char*)wls + 32768 + ol * 256;
            #pragma unroll
            for (int kb = 0; kb < 4; ++kb) {
                int ph16 = ((kb * 4 + kq) ^ key) << 4;
                bf16x8 b1 = *(const bf16x8*)(row1 + ph16);
                bf16x8 b2 = *(const bf16x8*)(row2 + ph16);
                acc1[nt] = __builtin_amdgcn_mfma_f32_16x16x32_bf16(av[kb], b1, acc1[nt], 0, 0, 0);
                acc2[nt] = __builtin_amdgcn_mfma_f32_16x16x32_bf16(av[kb], b2, acc2[nt], 0, 0, 0);
            }
        }
        u16* dst = ph ? bT : aT;
        #pragma unroll
        for (int nt = 0; nt < 8; ++nt) {
            int cc = nt * 16 + r;
            float b1v = B1[cc], b2v = B2[cc];
            float v0 = mkv[0] * sigm(acc1[nt][0] + b1v) * (acc2[nt][0] + b2v);
            float v1 = mkv[1] * sigm(acc1[nt][1] + b1v) * (acc2[nt][1] + b2v);
            float v2 = mkv[2] * sigm(acc1[nt][2] + b1v) * (acc2[nt][2] + b2v);
            float v3 = mkv[3] * sigm(acc1[nt][3] + b1v) * (acc2[nt][3] + b2v);
            u32x2 pv; pv.x = pack2(v0, v1); pv.y = pack2(v2, v3);
            *(u32x2*)((char*)dst + ((long)cc << 19) + boff) = pv;
        }
    }

    // gate phase: mfma(W, zn) swapped -> j-regs = 4 consecutive c
    __syncthreads();   // pair-B wls reads done
    {
        const char* Wg = (const char*)wbf + 131072;   // mat 4 (32KB)
        #pragma unroll
        for (int it = 0; it < 4; ++it)
            gl_lds16(Wg + (long)it * 8192 + tid * 16, (char*)wls + it * 8192 + w * 1024);
    }
    __syncthreads();
    {
        f32x4 acc[8];
        #pragma unroll
        for (int nt = 0; nt < 8; ++nt) acc[nt] = {0,0,0,0};
        #pragma unroll
        for (int nt = 0; nt < 8; ++nt) {
            int ol = nt * 16 + r;
            int key = ol & 7;
            const char* row1 = (const char*)wls + ol * 256;
            #pragma unroll
            for (int kb = 0; kb < 4; ++kb) {
                bf16x8 b1 = *(const bf16x8*)(row1 + (((kb * 4 + kq) ^ key) << 4));
                acc[nt] = __builtin_amdgcn_mfma_f32_16x16x32_bf16(b1, av[kb], acc[nt], 0, 0, 0);
            }
        }
        #pragma unroll
        for (int nt = 0; nt < 8; ++nt) {
            int c0 = nt * 16 + kq * 4;
            f32x4 bg = *(const f32x4*)(bias2 + 4 * CCH + c0);
            u32x2 pv;
            pv.x = pack2(sigm(acc[nt][0] + bg[0]), sigm(acc[nt][1] + bg[1]));
            pv.y = pack2(sigm(acc[nt][2] + bg[2]), sigm(acc[nt][3] + bg[3]));
            *(u32x2*)(gateB + mrow * 256 + c0) = pv;
        }
    }
}

// ---------------- k_tri: per-channel triangle GEMM, BK=64 ------------------
// Epilogue: accs -> LDS tile -> full-line row-major stores.
__global__ __launch_bounds__(256, 4) void k_tri(const u16* __restrict__ aT,
                                                const u16* __restrict__ bT,
                                                u16* __restrict__ xT) {
    __shared__ __align__(16) char shm[34816];  // At 16KB | Bt 16KB ; epilogue tile 34KB
    u16* At = (u16*)shm;
    u16* Bt = (u16*)(shm + 16384);
    int tid = threadIdx.x;
    int w = tid >> 6, lane = tid & 63;
    int r = lane & 15, kq = lane >> 4;

    int L = blockIdx.x;
    int xcd = L & 7, idx = L >> 3;
    int c    = xcd + 8 * (idx >> 4);
    int tile = idx & 15;
    int ti = tile >> 2, tj = tile & 3;

    const char* abase = (const char*)(aT + (long)c * MM) + (long)(ti * 128) * 1024;
    const char* bbase = (const char*)(bT + (long)c * MM) + (long)(tj * 128) * 1024;
    int wm = w >> 1, wn = w & 1;

    f32x4 acc[4][4];
    #pragma unroll
    for (int a = 0; a < 4; ++a)
        #pragma unroll
        for (int bq = 0; bq < 4; ++bq) acc[a][bq] = {0.f,0.f,0.f,0.f};

    for (int ks = 0; ks < 8; ++ks) {
        const char* asrc = abase + ks * 128;
        const char* bsrc = bbase + ks * 128;
        #pragma unroll
        for (int it = 0; it < 4; ++it) {
            int u = it * 256 + tid;
            long goff = (long)(u >> 3) * 1024 + (u & 7) * 16;
            gl_lds16(asrc + goff, (char*)At + it * 4096 + w * 1024);
            gl_lds16(bsrc + goff, (char*)Bt + it * 4096 + w * 1024);
        }
        __syncthreads();

        #pragma unroll
        for (int kh = 0; kh < 2; ++kh) {
            bf16x8 af[4];
            #pragma unroll
            for (int mt = 0; mt < 4; ++mt) {
                int rowa = wm * 64 + mt * 16 + r;
                af[mt] = *(const bf16x8*)((const char*)At + rowa * 128 +
                                          (((kh * 4 + kq) ^ (r & 7)) << 4));
            }
            #pragma unroll
            for (int nt = 0; nt < 4; ++nt) {
                int rowb = wn * 64 + nt * 16 + r;
                bf16x8 bf = *(const bf16x8*)((const char*)Bt + rowb * 128 +
                                             (((kh * 4 + kq) ^ (r & 7)) << 4));
                #pragma unroll
                for (int mt = 0; mt < 4; ++mt)
                    acc[mt][nt] = __builtin_amdgcn_mfma_f32_16x16x32_bf16(bf, af[mt], acc[mt][nt], 0, 0, 0);
            }
        }
        __syncthreads();   // also fences LDS before epilogue reuse (last iter)
    }

    // accs -> LDS tile [128 i][272B pitch] (col r = i-row, j-regs = 4 consecutive j)
    char* tb = shm;
    #pragma unroll
    for (int mt = 0; mt < 4; ++mt) {
        int il = wm * 64 + mt * 16 + r;
        #pragma unroll
        for (int nt = 0; nt < 4; ++nt) {
            int jl = wn * 64 + nt * 16 + kq * 4;
            u32x2 pv;
            pv.x = pack2(acc[mt][nt][0], acc[mt][nt][1]);
            pv.y = pack2(acc[mt][nt][2], acc[mt][nt][3]);
            *(u32x2*)(tb + il * 272 + jl * 2) = pv;
        }
    }
    __syncthreads();
    // store: 8 rounds x (4 rows x 256B contiguous per inst)
    u16* xrow = xT + (long)c * MM + (long)(ti * 128) * NN + tj * 128;
    int joff = tid & 15;
    #pragma unroll
    for (int rd = 0; rd < 8; ++rd) {
        int il = rd * 16 + (tid >> 4);
        u32x4 vv = *(const u32x4*)(tb + il * 272 + joff * 16);
        *(u32x4*)(xrow + (long)il * NN + joff * 8) = vv;
    }
}

// ---------------- k_out: LN(x) @ w_z''^T + bias2_z, * gate -----------------
// swapped mfma: j-regs -> 4 consecutive c -> f32x4 stores
__global__ __launch_bounds__(256, 4) void k_out(const u16* __restrict__ xT,
                                                const u16* __restrict__ wbf,
                                                const float* __restrict__ bias2,
                                                const u16* gateB,
                                                float* __restrict__ outp) {
    __shared__ __align__(16) u16 xl[64 * 128];  // 16KB
    int tid = threadIdx.x, w = tid >> 6, lane = tid & 63;
    int r = lane & 15, kq = lane >> 4;
    long m0 = (long)blockIdx.x * 64;

    // transpose stage: xT[c][m] -> xl[m][c], 4 channels packed per u16x4
    {
        int cg = tid & 31, ms = tid >> 5;
        int c0 = cg * 4;
        const u16* base = xT + m0 + (long)ms * 8;
        bf16x8 v0 = *(const bf16x8*)(base + (long)(c0 + 0) * MM);
        bf16x8 v1 = *(const bf16x8*)(base + (long)(c0 + 1) * MM);
        bf16x8 v2 = *(const bf16x8*)(base + (long)(c0 + 2) * MM);
        bf16x8 v3 = *(const bf16x8*)(base + (long)(c0 + 3) * MM);
        #pragma unroll
        for (int e = 0; e < 8; ++e) {
            int m = ms * 8 + e;
            u16x4 t;
            t.x = (u16)v0[e]; t.y = (u16)v1[e]; t.z = (u16)v2[e]; t.w = (u16)v3[e];
            *(u16x4*)((char*)xl + m * 256 + ((c0 * 2) ^ ((m & 15) << 4))) = t;
        }
    }
    __syncthreads();

    // A-frags as u32 pairs + LN stats via mask/shift decode
    int mlr = w * 16 + r;
    int swm = (mlr & 15) << 4;
    u32x4 avu[4];
    float s = 0.f, s2 = 0.f;
    #pragma unroll
    for (int kb = 0; kb < 4; ++kb) {
        avu[kb] = *(const u32x4*)((const char*)xl + mlr * 256 + ((kb * 64 + kq * 16) ^ swm));
        #pragma unroll
        for (int p = 0; p < 4; ++p) {
            unsigned u = avu[kb][p];
            float flo = __builtin_bit_cast(float, u << 16);
            float fhi = __builtin_bit_cast(float, u & 0xFFFF0000u);
            s += flo + fhi;
            s2 = fmaf(flo, flo, s2);
            s2 = fmaf(fhi, fhi, s2);
        }
    }
    s  += __shfl_xor(s, 16);  s  += __shfl_xor(s, 32);
    s2 += __shfl_xor(s2, 16); s2 += __shfl_xor(s2, 32);
    float mu = s * (1.0f / CCH);
    float var = fmaxf(s2 * (1.0f / CCH) - mu * mu, 0.f);
    float rs = rsqrtf(var + 1e-5f);
    float nmu = -mu * rs;
    bf16x8 av[4];
    #pragma unroll
    for (int kb = 0; kb < 4; ++kb) {
        u32x4 o;
        #pragma unroll
        for (int p = 0; p < 4; ++p) {
            unsigned u = avu[kb][p];
            float flo = __builtin_bit_cast(float, u << 16);
            float fhi = __builtin_bit_cast(float, u & 0xFFFF0000u);
            o[p] = pack2(fmaf(flo, rs, nmu), fmaf(fhi, rs, nmu));
        }
        av[kb] = __builtin_bit_cast(bf16x8, o);
    }

    // gate preload (gateB aliases outp rows of THIS block only)
    long m = m0 + w * 16 + r;
    u16x4 gvu[8];
    #pragma unroll
    for (int nt = 0; nt < 8; ++nt)
        gvu[nt] = *(const u16x4*)(gateB + m * 256 + nt * 16 + kq * 4);

    // swapped MFMA vs w_z'' (global reads, chunk-swizzled layout)
    const char* Wz = (const char*)(wbf + 5 * 16384);
    f32x4 acc[8];
    #pragma unroll
    for (int nt = 0; nt < 8; ++nt) acc[nt] = {0,0,0,0};
    #pragma unroll
    for (int nt = 0; nt < 8; ++nt) {
        int ol = nt * 16 + r;
        int key = ol & 7;
        const char* row = Wz + ol * 256;
        #pragma unroll
        for (int kb = 0; kb < 4; ++kb) {
            bf16x8 bw = *(const bf16x8*)(row + (((kb * 4 + kq) ^ key) << 4));
            acc[nt] = __builtin_amdgcn_mfma_f32_16x16x32_bf16(bw, av[kb], acc[nt], 0, 0, 0);
        }
    }

    __syncthreads();   // ALL gate loads done before any aliasing store

    const float* b2z = bias2 + 5 * CCH;
    #pragma unroll
    for (int nt = 0; nt < 8; ++nt) {
        int c0 = nt * 16 + kq * 4;
        f32x4 bb = *(const f32x4*)(b2z + c0);
        f32x4 o;
        #pragma unroll
        for (int j = 0; j < 4; ++j)
            o[j] = (acc[nt][j] + bb[j]) * bf2f(gvu[nt][j]);
        *(f32x4*)(outp + m * CCH + c0) = o;
    }
}

extern "C" void kernel_launch(void* const* d_in, const int* in_sizes, int n_in,
                              void* d_out, int out_size, void* d_ws, size_t ws_size,
                              hipStream_t stream) {
    const float* z       = (const float*)d_in[0];
    const float* mask    = (const float*)d_in[1];
    const float* ln_in_g = (const float*)d_in[2];
    const float* ln_in_b = (const float*)d_in[3];
    const float* w_ag    = (const float*)d_in[4];
    const float* b_ag    = (const float*)d_in[5];
    const float* w_ap    = (const float*)d_in[6];
    const float* b_ap    = (const float*)d_in[7];
    const float* w_bg    = (const float*)d_in[8];
    const float* b_bg    = (const float*)d_in[9];
    const float* w_bp    = (const float*)d_in[10];
    const float* b_bp    = (const float*)d_in[11];
    const float* w_g     = (const float*)d_in[12];
    const float* b_g     = (const float*)d_in[13];
    const float* w_z     = (const float*)d_in[14];
    const float* b_z     = (const float*)d_in[15];
    const float* ln_o_g  = (const float*)d_in[16];
    const float* ln_o_b  = (const float*)d_in[17];
    float* out = (float*)d_out;
    u16* gateB = (u16*)d_out;   // gate bf16 in first 256B of each 512B d_out row

    char* ws = (char*)d_ws;
    const size_t SL = (size_t)MM * CCH * 2;  // 64MB per slot
    u16* xT   = (u16*)ws;
    u16* aT   = (u16*)(ws + SL);
    u16* bT   = (u16*)(ws + 2 * SL);
    u16* wbf  = (u16*)(ws + 3 * SL);                       // 192KB swizzled bf16 weights
    float* b2 = (float*)(ws + 3 * SL + 6 * 16384 * 2);     // 3KB folded biases

    k_prep<<<6, 256, 0, stream>>>(w_ag, w_ap, w_bg, w_bp, w_g, w_z,
                                  b_ag, b_ap, b_bg, b_bp, b_g, b_z,
                                  ln_in_g, ln_in_b, ln_o_g, ln_o_b, wbf, b2);
    k_fused<<<MM / 128, 512, 0, stream>>>(z, mask, wbf, b2, aT, bT, gateB);
    k_tri<<<2048, 256, 0, stream>>>(aT, bT, xT);
    k_out<<<MM / 64, 256, 0, stream>>>(xT, wbf, b2, gateB, out);
}

// Round 13
// 291.694 us; speedup vs baseline: 1.8434x; 1.0671x over previous
//
#include <hip/hip_runtime.h>

#define NN 512
#define CCH 128
#define MM (NN*NN)   // 262144

using f32x4  = __attribute__((ext_vector_type(4))) float;
using f32x2  = __attribute__((ext_vector_type(2))) float;
using bf16x8 = __attribute__((ext_vector_type(8))) short;
using u16x4  = __attribute__((ext_vector_type(4))) unsigned short;
using u32x2  = __attribute__((ext_vector_type(2))) unsigned int;
using u32x4  = __attribute__((ext_vector_type(4))) unsigned int;
typedef unsigned short u16;

__device__ __forceinline__ u16 f2bf(float f) {
    unsigned u = __builtin_bit_cast(unsigned, f);
    u += 0x7FFF + ((u >> 16) & 1);
    return (u16)(u >> 16);
}
__device__ __forceinline__ float bf2f(u16 h) {
    unsigned u = ((unsigned)h) << 16;
    return __builtin_bit_cast(float, u);
}
__device__ __forceinline__ unsigned pack2(float lo, float hi) {
    return (unsigned)f2bf(lo) | ((unsigned)f2bf(hi) << 16);
}
__device__ __forceinline__ float sigm(float x) { return 1.0f / (1.0f + __expf(-x)); }

__device__ __forceinline__ void gl_lds16(const void* g, void* l) {
    __builtin_amdgcn_global_load_lds(
        (const __attribute__((address_space(1))) void*)g,
        (__attribute__((address_space(3))) void*)l, 16, 0, 0);
}

// ---------------- k_prep: fold LN gamma/beta into bf16 weights + biases ----
// Weight rows stored CHUNK-SWIZZLED: logical 16B chunk q of row o lives at
// physical chunk (q ^ (o&7)).
__global__ __launch_bounds__(256) void k_prep(
    const float* __restrict__ w0, const float* __restrict__ w1,
    const float* __restrict__ w2, const float* __restrict__ w3,
    const float* __restrict__ w4, const float* __restrict__ w5,
    const float* __restrict__ b0, const float* __restrict__ b1,
    const float* __restrict__ b2, const float* __restrict__ b3,
    const float* __restrict__ b4, const float* __restrict__ b5,
    const float* __restrict__ gin, const float* __restrict__ bin,
    const float* __restrict__ gout, const float* __restrict__ bout,
    u16* __restrict__ wbf, float* __restrict__ bias2) {
    int mat = blockIdx.x;
    const float* W = mat==0?w0:mat==1?w1:mat==2?w2:mat==3?w3:mat==4?w4:w5;
    const float* B = mat==0?b0:mat==1?b1:mat==2?b2:mat==3?b3:mat==4?b4:b5;
    const float* G = (mat==5)? gout : gin;
    const float* Bt= (mat==5)? bout : bin;
    __shared__ float gs[CCH], bs[CCH];
    int tid = threadIdx.x;
    if (tid < CCH) { gs[tid] = G[tid]; bs[tid] = Bt[tid]; }
    __syncthreads();
    int o = tid >> 1, c0 = (tid & 1) * 64;
    const float* src = W + o * CCH + c0;
    char* dstrow = (char*)(wbf + mat * 16384) + o * 256;
    int key = o & 7;
    float dot = 0.f;
    #pragma unroll
    for (int q = 0; q < 16; ++q) {
        f32x4 v = *(const f32x4*)(src + q * 4);
        int c = c0 + q * 4;
        dot += bs[c]*v.x + bs[c+1]*v.y + bs[c+2]*v.z + bs[c+3]*v.w;
        u16x4 p;
        p.x = f2bf(v.x * gs[c]);     p.y = f2bf(v.y * gs[c+1]);
        p.z = f2bf(v.z * gs[c+2]);   p.w = f2bf(v.w * gs[c+3]);
        int chunk = (c0 >> 3) + (q >> 1);
        *(u16x4*)(dstrow + (((chunk ^ key)) << 4) + ((q & 1) << 3)) = p;
    }
    dot += __shfl_xor(dot, 1);
    if ((tid & 1) == 0) bias2[mat * CCH + o] = B[o] + dot;
}

// ---------------- k_fused: LN(z) + all 5 projections, 128 rows/block -------
// 512 threads (8 waves). LN in REGISTERS. LDS = 64KB weights (2 matrices).
// Stage-early pipeline: next weights are issued right after the post-MFMA
// barrier; the previous epilogue executes between issue and drain-barrier.
__global__ __launch_bounds__(512, 4) void k_fused(
    const float* __restrict__ z, const float* __restrict__ mask,
    const u16* __restrict__ wbf, const float* __restrict__ bias2,
    u16* __restrict__ aT, u16* __restrict__ bT, u16* gateB) {
    __shared__ __align__(16) u16 wls[32768];   // 64KB: two 32KB weight matrices
    int tid = threadIdx.x, w = tid >> 6, lane = tid & 63;
    int r = lane & 15, kq = lane >> 4;
    long m0 = (long)blockIdx.x * 128;

    // stage pair-A weights (mats 0,1 contiguous 64KB) — hides under LN
    {
        const char* Wg = (const char*)wbf;
        #pragma unroll
        for (int it = 0; it < 8; ++it)
            gl_lds16(Wg + (long)it * 8192 + tid * 16, (char*)wls + it * 8192 + w * 1024);
    }

    // LN in registers: lane (w,r,kq) owns row m0+w*16+r, channels kb*32+kq*8+e
    long mrow = m0 + w * 16 + r;
    bf16x8 av[4];
    {
        const float* zr = z + mrow * CCH;
        f32x4 zv[4][2];
        float s = 0.f, s2 = 0.f;
        #pragma unroll
        for (int kb = 0; kb < 4; ++kb) {
            zv[kb][0] = *(const f32x4*)(zr + kb * 32 + kq * 8);
            zv[kb][1] = *(const f32x4*)(zr + kb * 32 + kq * 8 + 4);
            #pragma unroll
            for (int h = 0; h < 2; ++h) {
                f32x4 v = zv[kb][h];
                s += v.x + v.y + v.z + v.w;
                s2 = fmaf(v.x, v.x, fmaf(v.y, v.y, fmaf(v.z, v.z, fmaf(v.w, v.w, s2))));
            }
        }
        s  += __shfl_xor(s, 16);  s  += __shfl_xor(s, 32);
        s2 += __shfl_xor(s2, 16); s2 += __shfl_xor(s2, 32);
        float mu = s * (1.0f / CCH);
        float var = fmaxf(s2 * (1.0f / CCH) - mu * mu, 0.f);
        float rs = rsqrtf(var + 1e-5f);
        #pragma unroll
        for (int kb = 0; kb < 4; ++kb) {
            f32x4 a0 = zv[kb][0], a1 = zv[kb][1];
            u32x4 o;
            o[0] = pack2((a0.x - mu) * rs, (a0.y - mu) * rs);
            o[1] = pack2((a0.z - mu) * rs, (a0.w - mu) * rs);
            o[2] = pack2((a1.x - mu) * rs, (a1.y - mu) * rs);
            o[3] = pack2((a1.z - mu) * rs, (a1.w - mu) * rs);
            av[kb] = __builtin_bit_cast(bf16x8, o);
        }
    }
    f32x4 mkv = *(const f32x4*)(mask + m0 + w * 16 + kq * 4);

    // bias preload for pair A (overlaps pair-A staging drain)
    float b1v[4][2], b2v[4][2];   // [nt/2 grouping kept simple: 8 nt -> [4][2]]
    #pragma unroll
    for (int nt = 0; nt < 8; ++nt) {
        b1v[nt >> 1][nt & 1] = bias2[0 * CCH + nt * 16 + r];
        b2v[nt >> 1][nt & 1] = bias2[1 * CCH + nt * 16 + r];
    }

    int i7 = (int)((blockIdx.x >> 2) & 7);
    int q = w * 2 + (kq >> 1);                 // m_local/8 in [0,16)
    long boff = m0 * 2 + ((long)(q >> 3) << 7) + ((long)((q & 7) ^ i7) << 4)
              + ((kq & 1) << 3);

    __syncthreads();   // pair-A staging drained

    // ---- pair A: MFMA ----
    f32x4 acc1[8], acc2[8];
    #pragma unroll
    for (int nt = 0; nt < 8; ++nt) { acc1[nt] = {0,0,0,0}; acc2[nt] = {0,0,0,0}; }
    #pragma unroll
    for (int nt = 0; nt < 8; ++nt) {
        int ol = nt * 16 + r;
        int key = ol & 7;
        const char* row1 = (const char*)wls + ol * 256;
        const char* row2 = (const char*)wls + 32768 + ol * 256;
        #pragma unroll
        for (int kb = 0; kb < 4; ++kb) {
            int ph16 = ((kb * 4 + kq) ^ key) << 4;
            bf16x8 b1 = *(const bf16x8*)(row1 + ph16);
            bf16x8 b2 = *(const bf16x8*)(row2 + ph16);
            acc1[nt] = __builtin_amdgcn_mfma_f32_16x16x32_bf16(av[kb], b1, acc1[nt], 0, 0, 0);
            acc2[nt] = __builtin_amdgcn_mfma_f32_16x16x32_bf16(av[kb], b2, acc2[nt], 0, 0, 0);
        }
    }
    __syncthreads();   // all pair-A wls reads done

    // issue pair-B staging (mats 2,3) — hides under pair-A epilogue
    {
        const char* Wg = (const char*)wbf + 65536;
        #pragma unroll
        for (int it = 0; it < 8; ++it)
            gl_lds16(Wg + (long)it * 8192 + tid * 16, (char*)wls + it * 8192 + w * 1024);
    }

    // ---- pair A epilogue -> aT ----
    #pragma unroll
    for (int nt = 0; nt < 8; ++nt) {
        int cc = nt * 16 + r;
        float bb1 = b1v[nt >> 1][nt & 1], bb2 = b2v[nt >> 1][nt & 1];
        float v0 = mkv[0] * sigm(acc1[nt][0] + bb1) * (acc2[nt][0] + bb2);
        float v1 = mkv[1] * sigm(acc1[nt][1] + bb1) * (acc2[nt][1] + bb2);
        float v2 = mkv[2] * sigm(acc1[nt][2] + bb1) * (acc2[nt][2] + bb2);
        float v3 = mkv[3] * sigm(acc1[nt][3] + bb1) * (acc2[nt][3] + bb2);
        u32x2 pv; pv.x = pack2(v0, v1); pv.y = pack2(v2, v3);
        *(u32x2*)((char*)aT + ((long)cc << 19) + boff) = pv;
    }
    // bias preload for pair B
    #pragma unroll
    for (int nt = 0; nt < 8; ++nt) {
        b1v[nt >> 1][nt & 1] = bias2[2 * CCH + nt * 16 + r];
        b2v[nt >> 1][nt & 1] = bias2[3 * CCH + nt * 16 + r];
    }
    __syncthreads();   // pair-B staged & visible

    // ---- pair B: MFMA ----
    #pragma unroll
    for (int nt = 0; nt < 8; ++nt) { acc1[nt] = {0,0,0,0}; acc2[nt] = {0,0,0,0}; }
    #pragma unroll
    for (int nt = 0; nt < 8; ++nt) {
        int ol = nt * 16 + r;
        int key = ol & 7;
        const char* row1 = (const char*)wls + ol * 256;
        const char* row2 = (const char*)wls + 32768 + ol * 256;
        #pragma unroll
        for (int kb = 0; kb < 4; ++kb) {
            int ph16 = ((kb * 4 + kq) ^ key) << 4;
            bf16x8 b1 = *(const bf16x8*)(row1 + ph16);
            bf16x8 b2 = *(const bf16x8*)(row2 + ph16);
            acc1[nt] = __builtin_amdgcn_mfma_f32_16x16x32_bf16(av[kb], b1, acc1[nt], 0, 0, 0);
            acc2[nt] = __builtin_amdgcn_mfma_f32_16x16x32_bf16(av[kb], b2, acc2[nt], 0, 0, 0);
        }
    }
    __syncthreads();   // all pair-B wls reads done

    // issue gate staging (mat 4, 32KB) — hides under pair-B epilogue
    {
        const char* Wg = (const char*)wbf + 131072;
        #pragma unroll
        for (int it = 0; it < 4; ++it)
            gl_lds16(Wg + (long)it * 8192 + tid * 16, (char*)wls + it * 8192 + w * 1024);
    }

    // ---- pair B epilogue -> bT ----
    #pragma unroll
    for (int nt = 0; nt < 8; ++nt) {
        int cc = nt * 16 + r;
        float bb1 = b1v[nt >> 1][nt & 1], bb2 = b2v[nt >> 1][nt & 1];
        float v0 = mkv[0] * sigm(acc1[nt][0] + bb1) * (acc2[nt][0] + bb2);
        float v1 = mkv[1] * sigm(acc1[nt][1] + bb1) * (acc2[nt][1] + bb2);
        float v2 = mkv[2] * sigm(acc1[nt][2] + bb1) * (acc2[nt][2] + bb2);
        float v3 = mkv[3] * sigm(acc1[nt][3] + bb1) * (acc2[nt][3] + bb2);
        u32x2 pv; pv.x = pack2(v0, v1); pv.y = pack2(v2, v3);
        *(u32x2*)((char*)bT + ((long)cc << 19) + boff) = pv;
    }
    // gate bias preload
    f32x4 bg[8];
    #pragma unroll
    for (int nt = 0; nt < 8; ++nt)
        bg[nt] = *(const f32x4*)(bias2 + 4 * CCH + nt * 16 + kq * 4);
    __syncthreads();   // gate staged & visible

    // ---- gate: mfma(W, zn) swapped -> j-regs = 4 consecutive c ----
    {
        f32x4 acc[8];
        #pragma unroll
        for (int nt = 0; nt < 8; ++nt) acc[nt] = {0,0,0,0};
        #pragma unroll
        for (int nt = 0; nt < 8; ++nt) {
            int ol = nt * 16 + r;
            int key = ol & 7;
            const char* row1 = (const char*)wls + ol * 256;
            #pragma unroll
            for (int kb = 0; kb < 4; ++kb) {
                bf16x8 b1 = *(const bf16x8*)(row1 + (((kb * 4 + kq) ^ key) << 4));
                acc[nt] = __builtin_amdgcn_mfma_f32_16x16x32_bf16(b1, av[kb], acc[nt], 0, 0, 0);
            }
        }
        #pragma unroll
        for (int nt = 0; nt < 8; ++nt) {
            int c0 = nt * 16 + kq * 4;
            u32x2 pv;
            pv.x = pack2(sigm(acc[nt][0] + bg[nt][0]), sigm(acc[nt][1] + bg[nt][1]));
            pv.y = pack2(sigm(acc[nt][2] + bg[nt][2]), sigm(acc[nt][3] + bg[nt][3]));
            *(u32x2*)(gateB + mrow * 256 + c0) = pv;
        }
    }
}

// ---------------- k_tri: per-channel triangle GEMM, BK=64 ------------------
// Epilogue: accs -> LDS tile -> full-line row-major stores.
__global__ __launch_bounds__(256, 4) void k_tri(const u16* __restrict__ aT,
                                                const u16* __restrict__ bT,
                                                u16* __restrict__ xT) {
    __shared__ __align__(16) char shm[34816];  // At 16KB | Bt 16KB ; epilogue tile 34KB
    u16* At = (u16*)shm;
    u16* Bt = (u16*)(shm + 16384);
    int tid = threadIdx.x;
    int w = tid >> 6, lane = tid & 63;
    int r = lane & 15, kq = lane >> 4;

    int L = blockIdx.x;
    int xcd = L & 7, idx = L >> 3;
    int c    = xcd + 8 * (idx >> 4);
    int tile = idx & 15;
    int ti = tile >> 2, tj = tile & 3;

    const char* abase = (const char*)(aT + (long)c * MM) + (long)(ti * 128) * 1024;
    const char* bbase = (const char*)(bT + (long)c * MM) + (long)(tj * 128) * 1024;
    int wm = w >> 1, wn = w & 1;

    f32x4 acc[4][4];
    #pragma unroll
    for (int a = 0; a < 4; ++a)
        #pragma unroll
        for (int bq = 0; bq < 4; ++bq) acc[a][bq] = {0.f,0.f,0.f,0.f};

    for (int ks = 0; ks < 8; ++ks) {
        const char* asrc = abase + ks * 128;
        const char* bsrc = bbase + ks * 128;
        #pragma unroll
        for (int it = 0; it < 4; ++it) {
            int u = it * 256 + tid;
            long goff = (long)(u >> 3) * 1024 + (u & 7) * 16;
            gl_lds16(asrc + goff, (char*)At + it * 4096 + w * 1024);
            gl_lds16(bsrc + goff, (char*)Bt + it * 4096 + w * 1024);
        }
        __syncthreads();

        #pragma unroll
        for (int kh = 0; kh < 2; ++kh) {
            bf16x8 af[4];
            #pragma unroll
            for (int mt = 0; mt < 4; ++mt) {
                int rowa = wm * 64 + mt * 16 + r;
                af[mt] = *(const bf16x8*)((const char*)At + rowa * 128 +
                                          (((kh * 4 + kq) ^ (r & 7)) << 4));
            }
            #pragma unroll
            for (int nt = 0; nt < 4; ++nt) {
                int rowb = wn * 64 + nt * 16 + r;
                bf16x8 bf = *(const bf16x8*)((const char*)Bt + rowb * 128 +
                                             (((kh * 4 + kq) ^ (r & 7)) << 4));
                #pragma unroll
                for (int mt = 0; mt < 4; ++mt)
                    acc[mt][nt] = __builtin_amdgcn_mfma_f32_16x16x32_bf16(bf, af[mt], acc[mt][nt], 0, 0, 0);
            }
        }
        __syncthreads();   // also fences LDS before epilogue reuse (last iter)
    }

    // accs -> LDS tile [128 i][272B pitch] (col r = i-row, j-regs = 4 consecutive j)
    char* tb = shm;
    #pragma unroll
    for (int mt = 0; mt < 4; ++mt) {
        int il = wm * 64 + mt * 16 + r;
        #pragma unroll
        for (int nt = 0; nt < 4; ++nt) {
            int jl = wn * 64 + nt * 16 + kq * 4;
            u32x2 pv;
            pv.x = pack2(acc[mt][nt][0], acc[mt][nt][1]);
            pv.y = pack2(acc[mt][nt][2], acc[mt][nt][3]);
            *(u32x2*)(tb + il * 272 + jl * 2) = pv;
        }
    }
    __syncthreads();
    // store: 8 rounds x (4 rows x 256B contiguous per inst)
    u16* xrow = xT + (long)c * MM + (long)(ti * 128) * NN + tj * 128;
    int joff = tid & 15;
    #pragma unroll
    for (int rd = 0; rd < 8; ++rd) {
        int il = rd * 16 + (tid >> 4);
        u32x4 vv = *(const u32x4*)(tb + il * 272 + joff * 16);
        *(u32x4*)(xrow + (long)il * NN + joff * 8) = vv;
    }
}

// ---------------- k_out: LN(x) @ w_z''^T + bias2_z, * gate -----------------
// swapped mfma: j-regs -> 4 consecutive c -> f32x4 stores
__global__ __launch_bounds__(256, 4) void k_out(const u16* __restrict__ xT,
                                                const u16* __restrict__ wbf,
                                                const float* __restrict__ bias2,
                                                const u16* gateB,
                                                float* __restrict__ outp) {
    __shared__ __align__(16) u16 xl[64 * 128];  // 16KB
    int tid = threadIdx.x, w = tid >> 6, lane = tid & 63;
    int r = lane & 15, kq = lane >> 4;
    long m0 = (long)blockIdx.x * 64;

    // transpose stage: xT[c][m] -> xl[m][c], 4 channels packed per u16x4
    {
        int cg = tid & 31, ms = tid >> 5;
        int c0 = cg * 4;
        const u16* base = xT + m0 + (long)ms * 8;
        bf16x8 v0 = *(const bf16x8*)(base + (long)(c0 + 0) * MM);
        bf16x8 v1 = *(const bf16x8*)(base + (long)(c0 + 1) * MM);
        bf16x8 v2 = *(const bf16x8*)(base + (long)(c0 + 2) * MM);
        bf16x8 v3 = *(const bf16x8*)(base + (long)(c0 + 3) * MM);
        #pragma unroll
        for (int e = 0; e < 8; ++e) {
            int m = ms * 8 + e;
            u16x4 t;
            t.x = (u16)v0[e]; t.y = (u16)v1[e]; t.z = (u16)v2[e]; t.w = (u16)v3[e];
            *(u16x4*)((char*)xl + m * 256 + ((c0 * 2) ^ ((m & 15) << 4))) = t;
        }
    }
    __syncthreads();

    // A-frags as u32 pairs + LN stats via mask/shift decode
    int mlr = w * 16 + r;
    int swm = (mlr & 15) << 4;
    u32x4 avu[4];
    float s = 0.f, s2 = 0.f;
    #pragma unroll
    for (int kb = 0; kb < 4; ++kb) {
        avu[kb] = *(const u32x4*)((const char*)xl + mlr * 256 + ((kb * 64 + kq * 16) ^ swm));
        #pragma unroll
        for (int p = 0; p < 4; ++p) {
            unsigned u = avu[kb][p];
            float flo = __builtin_bit_cast(float, u << 16);
            float fhi = __builtin_bit_cast(float, u & 0xFFFF0000u);
            s += flo + fhi;
            s2 = fmaf(flo, flo, s2);
            s2 = fmaf(fhi, fhi, s2);
        }
    }
    s  += __shfl_xor(s, 16);  s  += __shfl_xor(s, 32);
    s2 += __shfl_xor(s2, 16); s2 += __shfl_xor(s2, 32);
    float mu = s * (1.0f / CCH);
    float var = fmaxf(s2 * (1.0f / CCH) - mu * mu, 0.f);
    float rs = rsqrtf(var + 1e-5f);
    float nmu = -mu * rs;
    bf16x8 av[4];
    #pragma unroll
    for (int kb = 0; kb < 4; ++kb) {
        u32x4 o;
        #pragma unroll
        for (int p = 0; p < 4; ++p) {
            unsigned u = avu[kb][p];
            float flo = __builtin_bit_cast(float, u << 16);
            float fhi = __builtin_bit_cast(float, u & 0xFFFF0000u);
            o[p] = pack2(fmaf(flo, rs, nmu), fmaf(fhi, rs, nmu));
        }
        av[kb] = __builtin_bit_cast(bf16x8, o);
    }

    // gate + bias preload (gateB aliases outp rows of THIS block only)
    long m = m0 + w * 16 + r;
    u16x4 gvu[8];
    f32x4 bb[8];
    #pragma unroll
    for (int nt = 0; nt < 8; ++nt) {
        gvu[nt] = *(const u16x4*)(gateB + m * 256 + nt * 16 + kq * 4);
        bb[nt]  = *(const f32x4*)(bias2 + 5 * CCH + nt * 16 + kq * 4);
    }

    // swapped MFMA vs w_z'' (global reads, chunk-swizzled layout)
    const char* Wz = (const char*)(wbf + 5 * 16384);
    f32x4 acc[8];
    #pragma unroll
    for (int nt = 0; nt < 8; ++nt) acc[nt] = {0,0,0,0};
    #pragma unroll
    for (int nt = 0; nt < 8; ++nt) {
        int ol = nt * 16 + r;
        int key = ol & 7;
        const char* row = Wz + ol * 256;
        #pragma unroll
        for (int kb = 0; kb < 4; ++kb) {
            bf16x8 bw = *(const bf16x8*)(row + (((kb * 4 + kq) ^ key) << 4));
            acc[nt] = __builtin_amdgcn_mfma_f32_16x16x32_bf16(bw, av[kb], acc[nt], 0, 0, 0);
        }
    }

    __syncthreads();   // ALL gate loads done before any aliasing store

    #pragma unroll
    for (int nt = 0; nt < 8; ++nt) {
        int c0 = nt * 16 + kq * 4;
        f32x4 o;
        #pragma unroll
        for (int j = 0; j < 4; ++j)
            o[j] = (acc[nt][j] + bb[nt][j]) * bf2f(gvu[nt][j]);
        *(f32x4*)(outp + m * CCH + c0) = o;
    }
}

extern "C" void kernel_launch(void* const* d_in, const int* in_sizes, int n_in,
                              void* d_out, int out_size, void* d_ws, size_t ws_size,
                              hipStream_t stream) {
    const float* z       = (const float*)d_in[0];
    const float* mask    = (const float*)d_in[1];
    const float* ln_in_g = (const float*)d_in[2];
    const float* ln_in_b = (const float*)d_in[3];
    const float* w_ag    = (const float*)d_in[4];
    const float* b_ag    = (const float*)d_in[5];
    const float* w_ap    = (const float*)d_in[6];
    const float* b_ap    = (const float*)d_in[7];
    const float* w_bg    = (const float*)d_in[8];
    const float* b_bg    = (const float*)d_in[9];
    const float* w_bp    = (const float*)d_in[10];
    const float* b_bp    = (const float*)d_in[11];
    const float* w_g     = (const float*)d_in[12];
    const float* b_g     = (const float*)d_in[13];
    const float* w_z     = (const float*)d_in[14];
    const float* b_z     = (const float*)d_in[15];
    const float* ln_o_g  = (const float*)d_in[16];
    const float* ln_o_b  = (const float*)d_in[17];
    float* out = (float*)d_out;
    u16* gateB = (u16*)d_out;   // gate bf16 in first 256B of each 512B d_out row

    char* ws = (char*)d_ws;
    const size_t SL = (size_t)MM * CCH * 2;  // 64MB per slot
    u16* xT   = (u16*)ws;
    u16* aT   = (u16*)(ws + SL);
    u16* bT   = (u16*)(ws + 2 * SL);
    u16* wbf  = (u16*)(ws + 3 * SL);                       // 192KB swizzled bf16 weights
    float* b2 = (float*)(ws + 3 * SL + 6 * 16384 * 2);     // 3KB folded biases

    k_prep<<<6, 256, 0, stream>>>(w_ag, w_ap, w_bg, w_bp, w_g, w_z,
                                  b_ag, b_ap, b_bg, b_bp, b_g, b_z,
                                  ln_in_g, ln_in_b, ln_o_g, ln_o_b, wbf, b2);
    k_fused<<<MM / 128, 512, 0, stream>>>(z, mask, wbf, b2, aT, bT, gateB);
    k_tri<<<2048, 256, 0, stream>>>(aT, bT, xT);
    k_out<<<MM / 64, 256, 0, stream>>>(xT, wbf, b2, gateB, out);
}